// Round 1
// baseline (3599.406 us; speedup 1.0000x reference)
//
#include <hip/hip_runtime.h>
#include <hip/hip_bf16.h>
#include <math.h>

#define NTOK 196
#define NDIM 768
#define NB 64
#define NH 12
#define NA 197               // N+1
#define MAT (NTOK * NTOK)    // 38416
#define ATTN_HW (NA * NA)    // 38809
#define POLAR_ITERS 15

// ---------------- w: CLS->patch attention, head-mean, normalized ----------------
__global__ void k_w(const float* __restrict__ attn, float* __restrict__ wbuf) {
  int b = blockIdx.x;
  int tid = threadIdx.x;
  __shared__ float red[256];
  float w0 = 0.f;
  if (tid < NTOK) {
    size_t base = (size_t)b * NH * ATTN_HW + 1 + tid;
    #pragma unroll
    for (int h = 0; h < NH; ++h) w0 += attn[base + (size_t)h * ATTN_HW];
    w0 *= (1.f / NH);
  }
  red[tid] = (tid < NTOK) ? w0 : 0.f;
  __syncthreads();
  for (int s = 128; s > 0; s >>= 1) { if (tid < s) red[tid] += red[tid + s]; __syncthreads(); }
  float S = red[0];
  if (tid < NTOK) wbuf[b * NTOK + tid] = w0 / (S + 1e-8f);
}

// ---------------- Grams: G = (w .* X)(w .* X)^T, symmetric triangle tiling ----------------
__global__ void k_gram(const float* __restrict__ s, const float* __restrict__ t,
                       const float* __restrict__ wbuf, float* __restrict__ Gbuf) {
  int slot = blockIdx.y, b = slot >> 1, src = slot & 1;
  const float* X = (src ? t : s) + (size_t)b * NTOK * NDIM;
  const float* wb = wbuf + b * NTOK;
  int x = blockIdx.x, ti = 0;
  while (x >= ti + 1) { x -= ti + 1; ++ti; }
  int tj = x;                      // tj <= ti
  int ri = ti * 32, rj = tj * 32;
  __shared__ float As[32][33], Bs[32][33];
  __shared__ float wA[32], wB[32];
  int tid = threadIdx.x;
  if (tid < 32) wA[tid] = (ri + tid < NTOK) ? wb[ri + tid] : 0.f;
  else if (tid < 64) { int i = tid - 32; wB[i] = (rj + i < NTOK) ? wb[rj + i] : 0.f; }
  __syncthreads();
  float a00 = 0, a01 = 0, a10 = 0, a11 = 0;
  int ty = tid >> 4, tx = tid & 15;
  for (int k0 = 0; k0 < NDIM; k0 += 32) {
    for (int l = tid; l < 1024; l += 256) {
      int ii = l >> 5, kk = l & 31;
      int r = ri + ii;
      As[ii][kk] = (r < NTOK) ? wA[ii] * X[(size_t)r * NDIM + k0 + kk] : 0.f;
      r = rj + ii;
      Bs[ii][kk] = (r < NTOK) ? wB[ii] * X[(size_t)r * NDIM + k0 + kk] : 0.f;
    }
    __syncthreads();
    #pragma unroll
    for (int kk = 0; kk < 32; ++kk) {
      float p0 = As[ty][kk], p1 = As[ty + 16][kk];
      float q0 = Bs[tx][kk], q1 = Bs[tx + 16][kk];
      a00 += p0 * q0; a01 += p0 * q1; a10 += p1 * q0; a11 += p1 * q1;
    }
    __syncthreads();
  }
  float* G = Gbuf + (size_t)slot * MAT;
  int i0 = ri + ty, i1 = ri + ty + 16, j0 = rj + tx, j1 = rj + tx + 16;
  if (i0 < NTOK && j0 < NTOK) { G[i0 * NTOK + j0] = a00; G[j0 * NTOK + i0] = a00; }
  if (i0 < NTOK && j1 < NTOK) { G[i0 * NTOK + j1] = a01; G[j1 * NTOK + i0] = a01; }
  if (i1 < NTOK && j0 < NTOK) { G[i1 * NTOK + j0] = a10; G[j0 * NTOK + i1] = a10; }
  if (i1 < NTOK && j1 < NTOK) { G[i1 * NTOK + j1] = a11; G[j1 * NTOK + i1] = a11; }
}

// ---------------- double-center in place: P = J G J (+ridge), record trace ----------------
__global__ void k_center(float* __restrict__ Gbuf, float* __restrict__ trPb) {
  int slot = blockIdx.x;
  float* A = Gbuf + (size_t)slot * MAT;
  __shared__ float r[NTOK];
  __shared__ float red[256];
  __shared__ float gsh, dsh;
  int tid = threadIdx.x;
  float acc = 0.f;
  if (tid < NTOK) {
    for (int m = 0; m < NTOK; ++m) acc += A[m * NTOK + tid];   // col sums == row sums (symmetric)
    r[tid] = acc * (1.f / NTOK);
  }
  red[tid] = (tid < NTOK) ? acc * (1.f / NTOK) : 0.f;
  __syncthreads();
  for (int s = 128; s > 0; s >>= 1) { if (tid < s) red[tid] += red[tid + s]; __syncthreads(); }
  float g = red[0] * (1.f / NTOK);
  float tv = (tid < NTOK) ? (A[tid * NTOK + tid] - 2.f * r[tid] + g) : 0.f;
  __syncthreads();
  red[tid] = tv;
  __syncthreads();
  for (int s = 128; s > 0; s >>= 1) { if (tid < s) red[tid] += red[tid + s]; __syncthreads(); }
  if (tid == 0) {
    float tr = red[0];
    trPb[slot] = tr;                                  // pre-ridge trace (exact tr_s / tr_t)
    gsh = g;
    dsh = 1e-4f * fmaxf(tr, 0.f) * (1.f / NTOK);      // ridge for Cholesky of rank-deficient P
  }
  __syncthreads();
  float gg = gsh, dd = dsh;
  for (int idx = tid; idx < MAT; idx += 256) {
    int n = idx / NTOK, m = idx - n * NTOK;
    float v = A[idx] - r[n] - r[m] + gg;
    if (n == m) v += dd;
    A[idx] = v;
  }
}

// ---------------- in-place Cholesky (lower), zero upper ----------------
__global__ void k_chol(float* __restrict__ Gbuf) {
  int slot = blockIdx.x;
  float* A = Gbuf + (size_t)slot * MAT;
  __shared__ float col[NTOK];
  __shared__ float piv;
  int tid = threadIdx.x;
  for (int k = 0; k < NTOK; ++k) {
    if (tid == 0) { float p = sqrtf(fmaxf(A[k * NTOK + k], 1e-20f)); A[k * NTOK + k] = p; piv = p; }
    __syncthreads();
    float inv = 1.f / piv;
    for (int i = k + 1 + tid; i < NTOK; i += 256) {
      float v = A[i * NTOK + k] * inv;
      A[i * NTOK + k] = v;
      col[i] = v;
    }
    for (int j = k + 1 + tid; j < NTOK; j += 256) A[k * NTOK + j] = 0.f;  // zero upper row k
    __syncthreads();
    int nrem = NTOK - 1 - k;
    int total = nrem * (nrem + 1) / 2;
    for (int tt = tid; tt < total; tt += 256) {
      int a = (int)((sqrtf(8.f * tt + 1.f) - 1.f) * 0.5f);
      while ((a + 1) * (a + 2) / 2 <= tt) ++a;
      while (a * (a + 1) / 2 > tt) --a;
      int bb = tt - a * (a + 1) / 2;
      int i = k + 1 + a, j = k + 1 + bb;   // j <= i : lower triangle only
      A[i * NTOK + j] -= col[i] * col[j];
    }
    __syncthreads();
  }
}

// ---------------- F = Lp^T * Lq ----------------
__global__ void k_F(const float* __restrict__ Gbuf, float* __restrict__ Fbuf) {
  int b = blockIdx.y;
  const float* Lp = Gbuf + (size_t)(2 * b) * MAT;
  const float* Lq = Gbuf + (size_t)(2 * b + 1) * MAT;
  int ti = blockIdx.x / 7, tj = blockIdx.x % 7;
  int ri = ti * 32, cj = tj * 32;
  __shared__ float As[32][33], Bs[32][33];
  int tid = threadIdx.x, ty = tid >> 4, tx = tid & 15;
  float a00 = 0, a01 = 0, a10 = 0, a11 = 0;
  for (int k0 = 0; k0 < NTOK; k0 += 32) {
    for (int l = tid; l < 1024; l += 256) {
      int kk = l >> 5, ii = l & 31;
      int krow = k0 + kk;
      As[kk][ii] = (krow < NTOK && ri + ii < NTOK) ? Lp[(size_t)krow * NTOK + ri + ii] : 0.f;
      Bs[kk][ii] = (krow < NTOK && cj + ii < NTOK) ? Lq[(size_t)krow * NTOK + cj + ii] : 0.f;
    }
    __syncthreads();
    #pragma unroll
    for (int kk = 0; kk < 32; ++kk) {
      float p0 = As[kk][ty], p1 = As[kk][ty + 16];
      float q0 = Bs[kk][tx], q1 = Bs[kk][tx + 16];
      a00 += p0 * q0; a01 += p0 * q1; a10 += p1 * q0; a11 += p1 * q1;
    }
    __syncthreads();
  }
  float* F = Fbuf + (size_t)b * MAT;
  int i0 = ri + ty, i1 = ri + ty + 16, j0 = cj + tx, j1 = cj + tx + 16;
  if (i0 < NTOK && j0 < NTOK) F[i0 * NTOK + j0] = a00;
  if (i0 < NTOK && j1 < NTOK) F[i0 * NTOK + j1] = a01;
  if (i1 < NTOK && j0 < NTOK) F[i1 * NTOK + j0] = a10;
  if (i1 < NTOK && j1 < NTOK) F[i1 * NTOK + j1] = a11;
}

// ---------------- power iteration: sigma_max estimate -> 1/(1.1*sigma) ----------------
__global__ void k_pow(const float* __restrict__ Fbuf, float* __restrict__ nrmb) {
  int b = blockIdx.x;
  const float* F = Fbuf + (size_t)b * MAT;
  __shared__ float v[NTOK], u[NTOK];
  __shared__ float red[256];
  int tid = threadIdx.x;
  if (tid < NTOK) v[tid] = 1.f;
  __syncthreads();
  float lastsum = 1.f;
  for (int it = 0; it < 6; ++it) {
    float a = 0.f;
    if (tid < NTOK) { for (int j = 0; j < NTOK; ++j) a += F[tid * NTOK + j] * v[j]; }
    __syncthreads();
    if (tid < NTOK) u[tid] = a;
    __syncthreads();
    float a2 = 0.f;
    if (tid < NTOK) { for (int i = 0; i < NTOK; ++i) a2 += F[i * NTOK + tid] * u[i]; }
    red[tid] = (tid < NTOK) ? a2 * a2 : 0.f;
    __syncthreads();
    for (int s = 128; s > 0; s >>= 1) { if (tid < s) red[tid] += red[tid + s]; __syncthreads(); }
    float sum = red[0];
    lastsum = sum;
    float invn = rsqrtf(sum + 1e-30f);
    __syncthreads();
    if (tid < NTOK) v[tid] = a2 * invn;
    __syncthreads();
  }
  if (tid == 0) {
    float sig = sqrtf(sqrtf(lastsum));     // ||B v|| ~ sigma_max^2
    nrmb[b] = 1.f / (1.1f * sig + 1e-30f);
  }
}

// ---------------- X0 = F * invnorm ----------------
__global__ void k_scale(const float* __restrict__ Fbuf, const float* __restrict__ nrmb,
                        float* __restrict__ X) {
  int b = blockIdx.y;
  int idx = blockIdx.x * 256 + threadIdx.x;
  if (idx < MAT) X[(size_t)b * MAT + idx] = Fbuf[(size_t)b * MAT + idx] * nrmb[b];
}

// ---------------- Gp = X^T X (symmetric, triangle tiling) ----------------
__global__ void k_xtx(const float* __restrict__ Xb, float* __restrict__ Gp) {
  int b = blockIdx.y;
  const float* X = Xb + (size_t)b * MAT;
  int x = blockIdx.x, ti = 0;
  while (x >= ti + 1) { x -= ti + 1; ++ti; }
  int tj = x;
  int ri = ti * 32, cj = tj * 32;
  __shared__ float As[32][33], Bs[32][33];
  int tid = threadIdx.x, ty = tid >> 4, tx = tid & 15;
  float a00 = 0, a01 = 0, a10 = 0, a11 = 0;
  for (int k0 = 0; k0 < NTOK; k0 += 32) {
    for (int l = tid; l < 1024; l += 256) {
      int kk = l >> 5, ii = l & 31;
      int krow = k0 + kk;
      As[kk][ii] = (krow < NTOK && ri + ii < NTOK) ? X[(size_t)krow * NTOK + ri + ii] : 0.f;
      Bs[kk][ii] = (krow < NTOK && cj + ii < NTOK) ? X[(size_t)krow * NTOK + cj + ii] : 0.f;
    }
    __syncthreads();
    #pragma unroll
    for (int kk = 0; kk < 32; ++kk) {
      float p0 = As[kk][ty], p1 = As[kk][ty + 16];
      float q0 = Bs[kk][tx], q1 = Bs[kk][tx + 16];
      a00 += p0 * q0; a01 += p0 * q1; a10 += p1 * q0; a11 += p1 * q1;
    }
    __syncthreads();
  }
  float* G = Gp + (size_t)b * MAT;
  int i0 = ri + ty, i1 = ri + ty + 16, j0 = cj + tx, j1 = cj + tx + 16;
  if (i0 < NTOK && j0 < NTOK) { G[i0 * NTOK + j0] = a00; G[j0 * NTOK + i0] = a00; }
  if (i0 < NTOK && j1 < NTOK) { G[i0 * NTOK + j1] = a01; G[j1 * NTOK + i0] = a01; }
  if (i1 < NTOK && j0 < NTOK) { G[i1 * NTOK + j0] = a10; G[j0 * NTOK + i1] = a10; }
  if (i1 < NTOK && j1 < NTOK) { G[i1 * NTOK + j1] = a11; G[j1 * NTOK + i1] = a11; }
}

// ---------------- Xn = 1.5 X - 0.5 X * G ----------------
__global__ void k_nsup(const float* __restrict__ Xb, const float* __restrict__ Gp,
                       float* __restrict__ Xn) {
  int b = blockIdx.y;
  const float* X = Xb + (size_t)b * MAT;
  const float* G = Gp + (size_t)b * MAT;
  int ti = blockIdx.x / 7, tj = blockIdx.x % 7;
  int ri = ti * 32, cj = tj * 32;
  __shared__ float As[32][33], Bs[32][33];
  int tid = threadIdx.x, ty = tid >> 4, tx = tid & 15;
  float a00 = 0, a01 = 0, a10 = 0, a11 = 0;
  for (int k0 = 0; k0 < NTOK; k0 += 32) {
    for (int l = tid; l < 1024; l += 256) {
      int rr = l >> 5, cc = l & 31;
      As[rr][cc] = (ri + rr < NTOK && k0 + cc < NTOK) ? X[(size_t)(ri + rr) * NTOK + k0 + cc] : 0.f;
      Bs[rr][cc] = (k0 + rr < NTOK && cj + cc < NTOK) ? G[(size_t)(k0 + rr) * NTOK + cj + cc] : 0.f;
    }
    __syncthreads();
    #pragma unroll
    for (int kk = 0; kk < 32; ++kk) {
      float p0 = As[ty][kk], p1 = As[ty + 16][kk];
      float q0 = Bs[kk][tx], q1 = Bs[kk][tx + 16];
      a00 += p0 * q0; a01 += p0 * q1; a10 += p1 * q0; a11 += p1 * q1;
    }
    __syncthreads();
  }
  float* O = Xn + (size_t)b * MAT;
  int i0 = ri + ty, i1 = ri + ty + 16, j0 = cj + tx, j1 = cj + tx + 16;
  if (i0 < NTOK && j0 < NTOK) O[i0 * NTOK + j0] = 1.5f * X[i0 * NTOK + j0] - 0.5f * a00;
  if (i0 < NTOK && j1 < NTOK) O[i0 * NTOK + j1] = 1.5f * X[i0 * NTOK + j1] - 0.5f * a01;
  if (i1 < NTOK && j0 < NTOK) O[i1 * NTOK + j0] = 1.5f * X[i1 * NTOK + j0] - 0.5f * a10;
  if (i1 < NTOK && j1 < NTOK) O[i1 * NTOK + j1] = 1.5f * X[i1 * NTOK + j1] - 0.5f * a11;
}

// ---------------- nuclear_b = sum(U .* F) ----------------
__global__ void k_nuc(const float* __restrict__ U, const float* __restrict__ Fbuf,
                      float* __restrict__ nucb) {
  int b = blockIdx.x;
  int tid = threadIdx.x;
  const float* Ub = U + (size_t)b * MAT;
  const float* Fb = Fbuf + (size_t)b * MAT;
  float acc = 0.f;
  for (int idx = tid; idx < MAT; idx += 256) acc += Ub[idx] * Fb[idx];
  __shared__ float red[256];
  red[tid] = acc;
  __syncthreads();
  for (int s = 128; s > 0; s >>= 1) { if (tid < s) red[tid] += red[tid + s]; __syncthreads(); }
  if (tid == 0) nucb[b] = red[0];
}

// ---------------- loss = mean_b relu(trP + trQ - 2*nuc) ----------------
__global__ void k_final(const float* __restrict__ trPb, const float* __restrict__ nucb,
                        float* __restrict__ out) {
  int tid = threadIdx.x;  // 64 threads = 1 wave
  float v = fmaxf(trPb[2 * tid] + trPb[2 * tid + 1] - 2.f * nucb[tid], 0.f);
  #pragma unroll
  for (int off = 32; off; off >>= 1) v += __shfl_down(v, off);
  if (tid == 0) out[0] = v * (1.f / 64.f);
}

extern "C" void kernel_launch(void* const* d_in, const int* in_sizes, int n_in,
                              void* d_out, int out_size, void* d_ws, size_t ws_size,
                              hipStream_t stream) {
  (void)in_sizes; (void)n_in; (void)out_size; (void)ws_size;
  const float* s = (const float*)d_in[0];
  const float* t = (const float*)d_in[1];
  const float* attn = (const float*)d_in[2];
  float* out = (float*)d_out;

  float* W = (float*)d_ws;
  float* Gbuf = W;                              // 128 * MAT   (G -> P -> L, in place)
  float* Fbuf = Gbuf + (size_t)128 * MAT;       // 64 * MAT
  float* Xbuf = Fbuf + (size_t)64 * MAT;        // 64 * MAT
  float* Xnew = Xbuf + (size_t)64 * MAT;        // 64 * MAT
  float* Gpol = Xnew + (size_t)64 * MAT;        // 64 * MAT
  float* wbuf = Gpol + (size_t)64 * MAT;        // 64 * 196
  float* trPb = wbuf + (size_t)NB * NTOK;       // 128
  float* nucb = trPb + 128;                     // 64
  float* nrmb = nucb + 64;                      // 64

  k_w<<<NB, 256, 0, stream>>>(attn, wbuf);
  k_gram<<<dim3(28, 128), 256, 0, stream>>>(s, t, wbuf, Gbuf);
  k_center<<<128, 256, 0, stream>>>(Gbuf, trPb);
  k_chol<<<128, 256, 0, stream>>>(Gbuf);
  k_F<<<dim3(49, 64), 256, 0, stream>>>(Gbuf, Fbuf);
  k_pow<<<64, 256, 0, stream>>>(Fbuf, nrmb);
  k_scale<<<dim3(151, 64), 256, 0, stream>>>(Fbuf, nrmb, Xbuf);

  float* Xc = Xbuf;
  float* Xn = Xnew;
  for (int it = 0; it < POLAR_ITERS; ++it) {
    k_xtx<<<dim3(28, 64), 256, 0, stream>>>(Xc, Gpol);
    k_nsup<<<dim3(49, 64), 256, 0, stream>>>(Xc, Gpol, Xn);
    float* tmp = Xc; Xc = Xn; Xn = tmp;
  }

  k_nuc<<<64, 256, 0, stream>>>(Xc, Fbuf, nucb);
  k_final<<<1, 64, 0, stream>>>(trPb, nucb, out);
}

// Round 2
// 2505.793 us; speedup vs baseline: 1.4364x; 1.4364x over previous
//
#include <hip/hip_runtime.h>
#include <hip/hip_bf16.h>
#include <math.h>

#define NTOK 196
#define NDIM 768
#define NB 64
#define NH 12
#define NA 197               // N+1
#define MAT (NTOK * NTOK)    // 38416
#define ATTN_HW (NA * NA)    // 38809
#define POLAR_ITERS 15
#define LDP 197              // padded leading dim for LDS Cholesky (gcd(197%32,32)=1 -> conflict-free cols)
#define CHOL_LDS_BYTES (NTOK * LDP * 4)

// ---------------- w: CLS->patch attention, head-mean, normalized ----------------
__global__ void k_w(const float* __restrict__ attn, float* __restrict__ wbuf) {
  int b = blockIdx.x;
  int tid = threadIdx.x;
  __shared__ float red[256];
  float w0 = 0.f;
  if (tid < NTOK) {
    size_t base = (size_t)b * NH * ATTN_HW + 1 + tid;
    #pragma unroll
    for (int h = 0; h < NH; ++h) w0 += attn[base + (size_t)h * ATTN_HW];
    w0 *= (1.f / NH);
  }
  red[tid] = (tid < NTOK) ? w0 : 0.f;
  __syncthreads();
  for (int s = 128; s > 0; s >>= 1) { if (tid < s) red[tid] += red[tid + s]; __syncthreads(); }
  float S = red[0];
  if (tid < NTOK) wbuf[b * NTOK + tid] = w0 / (S + 1e-8f);
}

// ---------------- Grams: G = (w .* X)(w .* X)^T, symmetric triangle tiling ----------------
__global__ void k_gram(const float* __restrict__ s, const float* __restrict__ t,
                       const float* __restrict__ wbuf, float* __restrict__ Gbuf) {
  int slot = blockIdx.y, b = slot >> 1, src = slot & 1;
  const float* X = (src ? t : s) + (size_t)b * NTOK * NDIM;
  const float* wb = wbuf + b * NTOK;
  int x = blockIdx.x, ti = 0;
  while (x >= ti + 1) { x -= ti + 1; ++ti; }
  int tj = x;                      // tj <= ti
  int ri = ti * 32, rj = tj * 32;
  __shared__ float As[32][33], Bs[32][33];
  __shared__ float wA[32], wB[32];
  int tid = threadIdx.x;
  if (tid < 32) wA[tid] = (ri + tid < NTOK) ? wb[ri + tid] : 0.f;
  else if (tid < 64) { int i = tid - 32; wB[i] = (rj + i < NTOK) ? wb[rj + i] : 0.f; }
  __syncthreads();
  float a00 = 0, a01 = 0, a10 = 0, a11 = 0;
  int ty = tid >> 4, tx = tid & 15;
  for (int k0 = 0; k0 < NDIM; k0 += 32) {
    for (int l = tid; l < 1024; l += 256) {
      int ii = l >> 5, kk = l & 31;
      int r = ri + ii;
      As[ii][kk] = (r < NTOK) ? wA[ii] * X[(size_t)r * NDIM + k0 + kk] : 0.f;
      r = rj + ii;
      Bs[ii][kk] = (r < NTOK) ? wB[ii] * X[(size_t)r * NDIM + k0 + kk] : 0.f;
    }
    __syncthreads();
    #pragma unroll
    for (int kk = 0; kk < 32; ++kk) {
      float p0 = As[ty][kk], p1 = As[ty + 16][kk];
      float q0 = Bs[tx][kk], q1 = Bs[tx + 16][kk];
      a00 += p0 * q0; a01 += p0 * q1; a10 += p1 * q0; a11 += p1 * q1;
    }
    __syncthreads();
  }
  float* G = Gbuf + (size_t)slot * MAT;
  int i0 = ri + ty, i1 = ri + ty + 16, j0 = rj + tx, j1 = rj + tx + 16;
  if (i0 < NTOK && j0 < NTOK) { G[i0 * NTOK + j0] = a00; G[j0 * NTOK + i0] = a00; }
  if (i0 < NTOK && j1 < NTOK) { G[i0 * NTOK + j1] = a01; G[j1 * NTOK + i0] = a01; }
  if (i1 < NTOK && j0 < NTOK) { G[i1 * NTOK + j0] = a10; G[j0 * NTOK + i1] = a10; }
  if (i1 < NTOK && j1 < NTOK) { G[i1 * NTOK + j1] = a11; G[j1 * NTOK + i1] = a11; }
}

// ---------------- double-center in place: P = J G J (+ridge), record trace ----------------
__global__ void k_center(float* __restrict__ Gbuf, float* __restrict__ trPb) {
  int slot = blockIdx.x;
  float* A = Gbuf + (size_t)slot * MAT;
  __shared__ float r[NTOK];
  __shared__ float red[256];
  __shared__ float gsh, dsh;
  int tid = threadIdx.x;
  float acc = 0.f;
  if (tid < NTOK) {
    for (int m = 0; m < NTOK; ++m) acc += A[m * NTOK + tid];   // col sums == row sums (symmetric)
    r[tid] = acc * (1.f / NTOK);
  }
  red[tid] = (tid < NTOK) ? acc * (1.f / NTOK) : 0.f;
  __syncthreads();
  for (int s = 128; s > 0; s >>= 1) { if (tid < s) red[tid] += red[tid + s]; __syncthreads(); }
  float g = red[0] * (1.f / NTOK);
  float tv = (tid < NTOK) ? (A[tid * NTOK + tid] - 2.f * r[tid] + g) : 0.f;
  __syncthreads();
  red[tid] = tv;
  __syncthreads();
  for (int s = 128; s > 0; s >>= 1) { if (tid < s) red[tid] += red[tid + s]; __syncthreads(); }
  if (tid == 0) {
    float tr = red[0];
    trPb[slot] = tr;                                  // pre-ridge trace (exact tr_s / tr_t)
    gsh = g;
    dsh = 1e-4f * fmaxf(tr, 0.f) * (1.f / NTOK);      // ridge for Cholesky of rank-deficient P
  }
  __syncthreads();
  float gg = gsh, dd = dsh;
  for (int idx = tid; idx < MAT; idx += 256) {
    int n = idx / NTOK, m = idx - n * NTOK;
    float v = A[idx] - r[n] - r[m] + gg;
    if (n == m) v += dd;
    A[idx] = v;
  }
}

// ---------------- full-LDS in-place Cholesky (lower), zero upper on writeback ----------------
// One block per matrix. Whole 196x197-padded matrix in dynamic LDS (150.8 KiB).
// 196 pivot steps: sqrt pivot -> scale column (1 row/thread) -> rank-1 update of the
// lower trailing triangle via a 16x16 thread grid (no div/mod, no global traffic).
__global__ void k_chol_lds(float* __restrict__ Gbuf) {
  extern __shared__ float Ash[];          // NTOK * LDP
  __shared__ float colv[NTOK];
  __shared__ float pivinv;
  int slot = blockIdx.x;
  float* A = Gbuf + (size_t)slot * MAT;
  int tid = threadIdx.x;
  for (int idx = tid; idx < MAT; idx += 256) {
    int i = idx / NTOK, j = idx - i * NTOK;
    Ash[i * LDP + j] = A[idx];
  }
  __syncthreads();
  int tx = tid & 15, ty = tid >> 4;
  for (int k = 0; k < NTOK; ++k) {
    if (tid == 0) {
      float d = fmaxf(Ash[k * LDP + k], 1e-20f);
      float sq = sqrtf(d);
      Ash[k * LDP + k] = sq;
      pivinv = 1.f / sq;
    }
    __syncthreads();
    float inv = pivinv;
    int i = k + 1 + tid;
    if (i < NTOK) {
      float v = Ash[i * LDP + k] * inv;
      Ash[i * LDP + k] = v;
      colv[i] = v;
    }
    __syncthreads();
    int base = k + 1, nrem = NTOK - base;
    for (int ii = ty; ii < nrem; ii += 16) {
      float ci = colv[base + ii];
      int row = (base + ii) * LDP + base;
      for (int jj = tx; jj <= ii; jj += 16)
        Ash[row + jj] -= ci * colv[base + jj];
    }
    __syncthreads();
  }
  for (int idx = tid; idx < MAT; idx += 256) {
    int i = idx / NTOK, j = idx - i * NTOK;
    A[idx] = (j <= i) ? Ash[i * LDP + j] : 0.f;
  }
}

// ---------------- fallback: original global-memory Cholesky ----------------
__global__ void k_chol_global(float* __restrict__ Gbuf) {
  int slot = blockIdx.x;
  float* A = Gbuf + (size_t)slot * MAT;
  __shared__ float col[NTOK];
  __shared__ float piv;
  int tid = threadIdx.x;
  for (int k = 0; k < NTOK; ++k) {
    if (tid == 0) { float p = sqrtf(fmaxf(A[k * NTOK + k], 1e-20f)); A[k * NTOK + k] = p; piv = p; }
    __syncthreads();
    float inv = 1.f / piv;
    for (int i = k + 1 + tid; i < NTOK; i += 256) {
      float v = A[i * NTOK + k] * inv;
      A[i * NTOK + k] = v;
      col[i] = v;
    }
    for (int j = k + 1 + tid; j < NTOK; j += 256) A[k * NTOK + j] = 0.f;
    __syncthreads();
    int nrem = NTOK - 1 - k;
    int total = nrem * (nrem + 1) / 2;
    for (int tt = tid; tt < total; tt += 256) {
      int a = (int)((sqrtf(8.f * tt + 1.f) - 1.f) * 0.5f);
      while ((a + 1) * (a + 2) / 2 <= tt) ++a;
      while (a * (a + 1) / 2 > tt) --a;
      int bb = tt - a * (a + 1) / 2;
      int i = k + 1 + a, j = k + 1 + bb;
      A[i * NTOK + j] -= col[i] * col[j];
    }
    __syncthreads();
  }
}

// ---------------- F = Lp^T * Lq ----------------
__global__ void k_F(const float* __restrict__ Gbuf, float* __restrict__ Fbuf) {
  int b = blockIdx.y;
  const float* Lp = Gbuf + (size_t)(2 * b) * MAT;
  const float* Lq = Gbuf + (size_t)(2 * b + 1) * MAT;
  int ti = blockIdx.x / 7, tj = blockIdx.x % 7;
  int ri = ti * 32, cj = tj * 32;
  __shared__ float As[32][33], Bs[32][33];
  int tid = threadIdx.x, ty = tid >> 4, tx = tid & 15;
  float a00 = 0, a01 = 0, a10 = 0, a11 = 0;
  for (int k0 = 0; k0 < NTOK; k0 += 32) {
    for (int l = tid; l < 1024; l += 256) {
      int kk = l >> 5, ii = l & 31;
      int krow = k0 + kk;
      As[kk][ii] = (krow < NTOK && ri + ii < NTOK) ? Lp[(size_t)krow * NTOK + ri + ii] : 0.f;
      Bs[kk][ii] = (krow < NTOK && cj + ii < NTOK) ? Lq[(size_t)krow * NTOK + cj + ii] : 0.f;
    }
    __syncthreads();
    #pragma unroll
    for (int kk = 0; kk < 32; ++kk) {
      float p0 = As[kk][ty], p1 = As[kk][ty + 16];
      float q0 = Bs[kk][tx], q1 = Bs[kk][tx + 16];
      a00 += p0 * q0; a01 += p0 * q1; a10 += p1 * q0; a11 += p1 * q1;
    }
    __syncthreads();
  }
  float* F = Fbuf + (size_t)b * MAT;
  int i0 = ri + ty, i1 = ri + ty + 16, j0 = cj + tx, j1 = cj + tx + 16;
  if (i0 < NTOK && j0 < NTOK) F[i0 * NTOK + j0] = a00;
  if (i0 < NTOK && j1 < NTOK) F[i0 * NTOK + j1] = a01;
  if (i1 < NTOK && j0 < NTOK) F[i1 * NTOK + j0] = a10;
  if (i1 < NTOK && j1 < NTOK) F[i1 * NTOK + j1] = a11;
}

// ---------------- power iteration: sigma_max estimate -> 1/(1.1*sigma) ----------------
__global__ void k_pow(const float* __restrict__ Fbuf, float* __restrict__ nrmb) {
  int b = blockIdx.x;
  const float* F = Fbuf + (size_t)b * MAT;
  __shared__ float v[NTOK], u[NTOK];
  __shared__ float red[256];
  int tid = threadIdx.x;
  if (tid < NTOK) v[tid] = 1.f;
  __syncthreads();
  float lastsum = 1.f;
  for (int it = 0; it < 6; ++it) {
    float a = 0.f;
    if (tid < NTOK) { for (int j = 0; j < NTOK; ++j) a += F[tid * NTOK + j] * v[j]; }
    __syncthreads();
    if (tid < NTOK) u[tid] = a;
    __syncthreads();
    float a2 = 0.f;
    if (tid < NTOK) { for (int i = 0; i < NTOK; ++i) a2 += F[i * NTOK + tid] * u[i]; }
    red[tid] = (tid < NTOK) ? a2 * a2 : 0.f;
    __syncthreads();
    for (int s = 128; s > 0; s >>= 1) { if (tid < s) red[tid] += red[tid + s]; __syncthreads(); }
    float sum = red[0];
    lastsum = sum;
    float invn = rsqrtf(sum + 1e-30f);
    __syncthreads();
    if (tid < NTOK) v[tid] = a2 * invn;
    __syncthreads();
  }
  if (tid == 0) {
    float sig = sqrtf(sqrtf(lastsum));     // ||B v|| ~ sigma_max^2
    nrmb[b] = 1.f / (1.1f * sig + 1e-30f);
  }
}

// ---------------- X0 = F * invnorm ----------------
__global__ void k_scale(const float* __restrict__ Fbuf, const float* __restrict__ nrmb,
                        float* __restrict__ X) {
  int b = blockIdx.y;
  int idx = blockIdx.x * 256 + threadIdx.x;
  if (idx < MAT) X[(size_t)b * MAT + idx] = Fbuf[(size_t)b * MAT + idx] * nrmb[b];
}

// ---------------- Gp = X^T X (symmetric, triangle tiling) ----------------
__global__ void k_xtx(const float* __restrict__ Xb, float* __restrict__ Gp) {
  int b = blockIdx.y;
  const float* X = Xb + (size_t)b * MAT;
  int x = blockIdx.x, ti = 0;
  while (x >= ti + 1) { x -= ti + 1; ++ti; }
  int tj = x;
  int ri = ti * 32, cj = tj * 32;
  __shared__ float As[32][33], Bs[32][33];
  int tid = threadIdx.x, ty = tid >> 4, tx = tid & 15;
  float a00 = 0, a01 = 0, a10 = 0, a11 = 0;
  for (int k0 = 0; k0 < NTOK; k0 += 32) {
    for (int l = tid; l < 1024; l += 256) {
      int kk = l >> 5, ii = l & 31;
      int krow = k0 + kk;
      As[kk][ii] = (krow < NTOK && ri + ii < NTOK) ? X[(size_t)krow * NTOK + ri + ii] : 0.f;
      Bs[kk][ii] = (krow < NTOK && cj + ii < NTOK) ? X[(size_t)krow * NTOK + cj + ii] : 0.f;
    }
    __syncthreads();
    #pragma unroll
    for (int kk = 0; kk < 32; ++kk) {
      float p0 = As[kk][ty], p1 = As[kk][ty + 16];
      float q0 = Bs[kk][tx], q1 = Bs[kk][tx + 16];
      a00 += p0 * q0; a01 += p0 * q1; a10 += p1 * q0; a11 += p1 * q1;
    }
    __syncthreads();
  }
  float* G = Gp + (size_t)b * MAT;
  int i0 = ri + ty, i1 = ri + ty + 16, j0 = cj + tx, j1 = cj + tx + 16;
  if (i0 < NTOK && j0 < NTOK) { G[i0 * NTOK + j0] = a00; G[j0 * NTOK + i0] = a00; }
  if (i0 < NTOK && j1 < NTOK) { G[i0 * NTOK + j1] = a01; G[j1 * NTOK + i0] = a01; }
  if (i1 < NTOK && j0 < NTOK) { G[i1 * NTOK + j0] = a10; G[j0 * NTOK + i1] = a10; }
  if (i1 < NTOK && j1 < NTOK) { G[i1 * NTOK + j1] = a11; G[j1 * NTOK + i1] = a11; }
}

// ---------------- Xn = 1.5 X - 0.5 X * G ----------------
__global__ void k_nsup(const float* __restrict__ Xb, const float* __restrict__ Gp,
                       float* __restrict__ Xn) {
  int b = blockIdx.y;
  const float* X = Xb + (size_t)b * MAT;
  const float* G = Gp + (size_t)b * MAT;
  int ti = blockIdx.x / 7, tj = blockIdx.x % 7;
  int ri = ti * 32, cj = tj * 32;
  __shared__ float As[32][33], Bs[32][33];
  int tid = threadIdx.x, ty = tid >> 4, tx = tid & 15;
  float a00 = 0, a01 = 0, a10 = 0, a11 = 0;
  for (int k0 = 0; k0 < NTOK; k0 += 32) {
    for (int l = tid; l < 1024; l += 256) {
      int rr = l >> 5, cc = l & 31;
      As[rr][cc] = (ri + rr < NTOK && k0 + cc < NTOK) ? X[(size_t)(ri + rr) * NTOK + k0 + cc] : 0.f;
      Bs[rr][cc] = (k0 + rr < NTOK && cj + cc < NTOK) ? G[(size_t)(k0 + rr) * NTOK + cj + cc] : 0.f;
    }
    __syncthreads();
    #pragma unroll
    for (int kk = 0; kk < 32; ++kk) {
      float p0 = As[ty][kk], p1 = As[ty + 16][kk];
      float q0 = Bs[kk][tx], q1 = Bs[kk][tx + 16];
      a00 += p0 * q0; a01 += p0 * q1; a10 += p1 * q0; a11 += p1 * q1;
    }
    __syncthreads();
  }
  float* O = Xn + (size_t)b * MAT;
  int i0 = ri + ty, i1 = ri + ty + 16, j0 = cj + tx, j1 = cj + tx + 16;
  if (i0 < NTOK && j0 < NTOK) O[i0 * NTOK + j0] = 1.5f * X[i0 * NTOK + j0] - 0.5f * a00;
  if (i0 < NTOK && j1 < NTOK) O[i0 * NTOK + j1] = 1.5f * X[i0 * NTOK + j1] - 0.5f * a01;
  if (i1 < NTOK && j0 < NTOK) O[i1 * NTOK + j0] = 1.5f * X[i1 * NTOK + j0] - 0.5f * a10;
  if (i1 < NTOK && j1 < NTOK) O[i1 * NTOK + j1] = 1.5f * X[i1 * NTOK + j1] - 0.5f * a11;
}

// ---------------- nuclear_b = sum(U .* F) ----------------
__global__ void k_nuc(const float* __restrict__ U, const float* __restrict__ Fbuf,
                      float* __restrict__ nucb) {
  int b = blockIdx.x;
  int tid = threadIdx.x;
  const float* Ub = U + (size_t)b * MAT;
  const float* Fb = Fbuf + (size_t)b * MAT;
  float acc = 0.f;
  for (int idx = tid; idx < MAT; idx += 256) acc += Ub[idx] * Fb[idx];
  __shared__ float red[256];
  red[tid] = acc;
  __syncthreads();
  for (int s = 128; s > 0; s >>= 1) { if (tid < s) red[tid] += red[tid + s]; __syncthreads(); }
  if (tid == 0) nucb[b] = red[0];
}

// ---------------- loss = mean_b relu(trP + trQ - 2*nuc) ----------------
__global__ void k_final(const float* __restrict__ trPb, const float* __restrict__ nucb,
                        float* __restrict__ out) {
  int tid = threadIdx.x;  // 64 threads = 1 wave
  float v = fmaxf(trPb[2 * tid] + trPb[2 * tid + 1] - 2.f * nucb[tid], 0.f);
  #pragma unroll
  for (int off = 32; off; off >>= 1) v += __shfl_down(v, off);
  if (tid == 0) out[0] = v * (1.f / 64.f);
}

extern "C" void kernel_launch(void* const* d_in, const int* in_sizes, int n_in,
                              void* d_out, int out_size, void* d_ws, size_t ws_size,
                              hipStream_t stream) {
  (void)in_sizes; (void)n_in; (void)out_size; (void)ws_size;
  const float* s = (const float*)d_in[0];
  const float* t = (const float*)d_in[1];
  const float* attn = (const float*)d_in[2];
  float* out = (float*)d_out;

  float* W = (float*)d_ws;
  float* Gbuf = W;                              // 128 * MAT   (G -> P -> L, in place)
  float* Fbuf = Gbuf + (size_t)128 * MAT;       // 64 * MAT
  float* Xbuf = Fbuf + (size_t)64 * MAT;        // 64 * MAT
  float* Xnew = Xbuf + (size_t)64 * MAT;        // 64 * MAT
  float* Gpol = Xnew + (size_t)64 * MAT;        // 64 * MAT
  float* wbuf = Gpol + (size_t)64 * MAT;        // 64 * 196
  float* trPb = wbuf + (size_t)NB * NTOK;       // 128
  float* nucb = trPb + 128;                     // 64
  float* nrmb = nucb + 64;                      // 64

  k_w<<<NB, 256, 0, stream>>>(attn, wbuf);
  k_gram<<<dim3(28, 128), 256, 0, stream>>>(s, t, wbuf, Gbuf);
  k_center<<<128, 256, 0, stream>>>(Gbuf, trPb);

  // full-LDS Cholesky needs 150.8 KiB dynamic LDS (gfx950 has 160 KiB/CU) — opt in.
  hipError_t attr_ok = hipFuncSetAttribute(
      reinterpret_cast<const void*>(k_chol_lds),
      hipFuncAttributeMaxDynamicSharedMemorySize, CHOL_LDS_BYTES);
  if (attr_ok == hipSuccess) {
    k_chol_lds<<<128, 256, CHOL_LDS_BYTES, stream>>>(Gbuf);
  } else {
    k_chol_global<<<128, 256, 0, stream>>>(Gbuf);
  }

  k_F<<<dim3(49, 64), 256, 0, stream>>>(Gbuf, Fbuf);
  k_pow<<<64, 256, 0, stream>>>(Fbuf, nrmb);
  k_scale<<<dim3(151, 64), 256, 0, stream>>>(Fbuf, nrmb, Xbuf);

  float* Xc = Xbuf;
  float* Xn = Xnew;
  for (int it = 0; it < POLAR_ITERS; ++it) {
    k_xtx<<<dim3(28, 64), 256, 0, stream>>>(Xc, Gpol);
    k_nsup<<<dim3(49, 64), 256, 0, stream>>>(Xc, Gpol, Xn);
    float* tmp = Xc; Xc = Xn; Xn = tmp;
  }

  k_nuc<<<64, 256, 0, stream>>>(Xc, Fbuf, nucb);
  k_final<<<1, 64, 0, stream>>>(trPb, nucb, out);
}

// Round 3
// 2211.847 us; speedup vs baseline: 1.6273x; 1.1329x over previous
//
#include <hip/hip_runtime.h>
#include <hip/hip_bf16.h>
#include <math.h>

#define NTOK 196
#define NDIM 768
#define NB 64
#define NH 12
#define NA 197               // N+1
#define MAT (NTOK * NTOK)    // 38416
#define ATTN_HW (NA * NA)    // 38809
#define POLAR_ITERS 15
#define LDP 197              // padded leading dim for LDS Cholesky
#define CHOL_LDS_BYTES (NTOK * LDP * 4)

// fused polar constants
#define PADC 208             // 13*16 padded cols (and K) for MFMA tiling
#define NTILE 13
#define POLAR_LDS_BYTES (2 * NTOK * PADC * 2)   // X + Xt, bf16: 163072 B

typedef __attribute__((ext_vector_type(8))) short short8;
typedef __attribute__((ext_vector_type(4))) float f32x4;

__device__ inline short8 s8zero() { short8 z = {0,0,0,0,0,0,0,0}; return z; }

__device__ inline short f2bf(float f) {            // RNE fp32 -> bf16
  union { float f; unsigned u; } v; v.f = f;
  unsigned u = v.u;
  u += 0x7fffu + ((u >> 16) & 1u);
  return (short)(u >> 16);
}
__device__ inline float bf2f(short s) {
  union { unsigned u; float f; } v;
  v.u = ((unsigned)(unsigned short)s) << 16;
  return v.f;
}

// ---------------- w: CLS->patch attention, head-mean, normalized ----------------
__global__ void k_w(const float* __restrict__ attn, float* __restrict__ wbuf) {
  int b = blockIdx.x;
  int tid = threadIdx.x;
  __shared__ float red[256];
  float w0 = 0.f;
  if (tid < NTOK) {
    size_t base = (size_t)b * NH * ATTN_HW + 1 + tid;
    #pragma unroll
    for (int h = 0; h < NH; ++h) w0 += attn[base + (size_t)h * ATTN_HW];
    w0 *= (1.f / NH);
  }
  red[tid] = (tid < NTOK) ? w0 : 0.f;
  __syncthreads();
  for (int s = 128; s > 0; s >>= 1) { if (tid < s) red[tid] += red[tid + s]; __syncthreads(); }
  float S = red[0];
  if (tid < NTOK) wbuf[b * NTOK + tid] = w0 / (S + 1e-8f);
}

// ---------------- Grams: G = (w .* X)(w .* X)^T, symmetric triangle tiling ----------------
__global__ void k_gram(const float* __restrict__ s, const float* __restrict__ t,
                       const float* __restrict__ wbuf, float* __restrict__ Gbuf) {
  int slot = blockIdx.y, b = slot >> 1, src = slot & 1;
  const float* X = (src ? t : s) + (size_t)b * NTOK * NDIM;
  const float* wb = wbuf + b * NTOK;
  int x = blockIdx.x, ti = 0;
  while (x >= ti + 1) { x -= ti + 1; ++ti; }
  int tj = x;                      // tj <= ti
  int ri = ti * 32, rj = tj * 32;
  __shared__ float As[32][33], Bs[32][33];
  __shared__ float wA[32], wB[32];
  int tid = threadIdx.x;
  if (tid < 32) wA[tid] = (ri + tid < NTOK) ? wb[ri + tid] : 0.f;
  else if (tid < 64) { int i = tid - 32; wB[i] = (rj + i < NTOK) ? wb[rj + i] : 0.f; }
  __syncthreads();
  float a00 = 0, a01 = 0, a10 = 0, a11 = 0;
  int ty = tid >> 4, tx = tid & 15;
  for (int k0 = 0; k0 < NDIM; k0 += 32) {
    for (int l = tid; l < 1024; l += 256) {
      int ii = l >> 5, kk = l & 31;
      int r = ri + ii;
      As[ii][kk] = (r < NTOK) ? wA[ii] * X[(size_t)r * NDIM + k0 + kk] : 0.f;
      r = rj + ii;
      Bs[ii][kk] = (r < NTOK) ? wB[ii] * X[(size_t)r * NDIM + k0 + kk] : 0.f;
    }
    __syncthreads();
    #pragma unroll
    for (int kk = 0; kk < 32; ++kk) {
      float p0 = As[ty][kk], p1 = As[ty + 16][kk];
      float q0 = Bs[tx][kk], q1 = Bs[tx + 16][kk];
      a00 += p0 * q0; a01 += p0 * q1; a10 += p1 * q0; a11 += p1 * q1;
    }
    __syncthreads();
  }
  float* G = Gbuf + (size_t)slot * MAT;
  int i0 = ri + ty, i1 = ri + ty + 16, j0 = rj + tx, j1 = rj + tx + 16;
  if (i0 < NTOK && j0 < NTOK) { G[i0 * NTOK + j0] = a00; G[j0 * NTOK + i0] = a00; }
  if (i0 < NTOK && j1 < NTOK) { G[i0 * NTOK + j1] = a01; G[j1 * NTOK + i0] = a01; }
  if (i1 < NTOK && j0 < NTOK) { G[i1 * NTOK + j0] = a10; G[j0 * NTOK + i1] = a10; }
  if (i1 < NTOK && j1 < NTOK) { G[i1 * NTOK + j1] = a11; G[j1 * NTOK + i1] = a11; }
}

// ---------------- double-center in place: P = J G J (+ridge), record trace ----------------
__global__ void k_center(float* __restrict__ Gbuf, float* __restrict__ trPb) {
  int slot = blockIdx.x;
  float* A = Gbuf + (size_t)slot * MAT;
  __shared__ float r[NTOK];
  __shared__ float red[256];
  __shared__ float gsh, dsh;
  int tid = threadIdx.x;
  float acc = 0.f;
  if (tid < NTOK) {
    for (int m = 0; m < NTOK; ++m) acc += A[m * NTOK + tid];
    r[tid] = acc * (1.f / NTOK);
  }
  red[tid] = (tid < NTOK) ? acc * (1.f / NTOK) : 0.f;
  __syncthreads();
  for (int s = 128; s > 0; s >>= 1) { if (tid < s) red[tid] += red[tid + s]; __syncthreads(); }
  float g = red[0] * (1.f / NTOK);
  float tv = (tid < NTOK) ? (A[tid * NTOK + tid] - 2.f * r[tid] + g) : 0.f;
  __syncthreads();
  red[tid] = tv;
  __syncthreads();
  for (int s = 128; s > 0; s >>= 1) { if (tid < s) red[tid] += red[tid + s]; __syncthreads(); }
  if (tid == 0) {
    float tr = red[0];
    trPb[slot] = tr;
    gsh = g;
    dsh = 1e-4f * fmaxf(tr, 0.f) * (1.f / NTOK);
  }
  __syncthreads();
  float gg = gsh, dd = dsh;
  for (int idx = tid; idx < MAT; idx += 256) {
    int n = idx / NTOK, m = idx - n * NTOK;
    float v = A[idx] - r[n] - r[m] + gg;
    if (n == m) v += dd;
    A[idx] = v;
  }
}

// ---------------- full-LDS in-place Cholesky (lower), zero upper on writeback ----------------
__global__ void k_chol_lds(float* __restrict__ Gbuf) {
  extern __shared__ float Ash[];          // NTOK * LDP
  __shared__ float colv[NTOK];
  __shared__ float pivinv;
  int slot = blockIdx.x;
  float* A = Gbuf + (size_t)slot * MAT;
  int tid = threadIdx.x;
  for (int idx = tid; idx < MAT; idx += 256) {
    int i = idx / NTOK, j = idx - i * NTOK;
    Ash[i * LDP + j] = A[idx];
  }
  __syncthreads();
  int tx = tid & 15, ty = tid >> 4;
  for (int k = 0; k < NTOK; ++k) {
    if (tid == 0) {
      float d = fmaxf(Ash[k * LDP + k], 1e-20f);
      float sq = sqrtf(d);
      Ash[k * LDP + k] = sq;
      pivinv = 1.f / sq;
    }
    __syncthreads();
    float inv = pivinv;
    int i = k + 1 + tid;
    if (i < NTOK) {
      float v = Ash[i * LDP + k] * inv;
      Ash[i * LDP + k] = v;
      colv[i] = v;
    }
    __syncthreads();
    int base = k + 1, nrem = NTOK - base;
    for (int ii = ty; ii < nrem; ii += 16) {
      float ci = colv[base + ii];
      int row = (base + ii) * LDP + base;
      for (int jj = tx; jj <= ii; jj += 16)
        Ash[row + jj] -= ci * colv[base + jj];
    }
    __syncthreads();
  }
  for (int idx = tid; idx < MAT; idx += 256) {
    int i = idx / NTOK, j = idx - i * NTOK;
    A[idx] = (j <= i) ? Ash[i * LDP + j] : 0.f;
  }
}

// ---------------- fallback: original global-memory Cholesky ----------------
__global__ void k_chol_global(float* __restrict__ Gbuf) {
  int slot = blockIdx.x;
  float* A = Gbuf + (size_t)slot * MAT;
  __shared__ float col[NTOK];
  __shared__ float piv;
  int tid = threadIdx.x;
  for (int k = 0; k < NTOK; ++k) {
    if (tid == 0) { float p = sqrtf(fmaxf(A[k * NTOK + k], 1e-20f)); A[k * NTOK + k] = p; piv = p; }
    __syncthreads();
    float inv = 1.f / piv;
    for (int i = k + 1 + tid; i < NTOK; i += 256) {
      float v = A[i * NTOK + k] * inv;
      A[i * NTOK + k] = v;
      col[i] = v;
    }
    for (int j = k + 1 + tid; j < NTOK; j += 256) A[k * NTOK + j] = 0.f;
    __syncthreads();
    int nrem = NTOK - 1 - k;
    int total = nrem * (nrem + 1) / 2;
    for (int tt = tid; tt < total; tt += 256) {
      int a = (int)((sqrtf(8.f * tt + 1.f) - 1.f) * 0.5f);
      while ((a + 1) * (a + 2) / 2 <= tt) ++a;
      while (a * (a + 1) / 2 > tt) --a;
      int bb = tt - a * (a + 1) / 2;
      int i = k + 1 + a, j = k + 1 + bb;
      A[i * NTOK + j] -= col[i] * col[j];
    }
    __syncthreads();
  }
}

// ---------------- F = Lp^T * Lq ----------------
__global__ void k_F(const float* __restrict__ Gbuf, float* __restrict__ Fbuf) {
  int b = blockIdx.y;
  const float* Lp = Gbuf + (size_t)(2 * b) * MAT;
  const float* Lq = Gbuf + (size_t)(2 * b + 1) * MAT;
  int ti = blockIdx.x / 7, tj = blockIdx.x % 7;
  int ri = ti * 32, cj = tj * 32;
  __shared__ float As[32][33], Bs[32][33];
  int tid = threadIdx.x, ty = tid >> 4, tx = tid & 15;
  float a00 = 0, a01 = 0, a10 = 0, a11 = 0;
  for (int k0 = 0; k0 < NTOK; k0 += 32) {
    for (int l = tid; l < 1024; l += 256) {
      int kk = l >> 5, ii = l & 31;
      int krow = k0 + kk;
      As[kk][ii] = (krow < NTOK && ri + ii < NTOK) ? Lp[(size_t)krow * NTOK + ri + ii] : 0.f;
      Bs[kk][ii] = (krow < NTOK && cj + ii < NTOK) ? Lq[(size_t)krow * NTOK + cj + ii] : 0.f;
    }
    __syncthreads();
    #pragma unroll
    for (int kk = 0; kk < 32; ++kk) {
      float p0 = As[kk][ty], p1 = As[kk][ty + 16];
      float q0 = Bs[kk][tx], q1 = Bs[kk][tx + 16];
      a00 += p0 * q0; a01 += p0 * q1; a10 += p1 * q0; a11 += p1 * q1;
    }
    __syncthreads();
  }
  float* F = Fbuf + (size_t)b * MAT;
  int i0 = ri + ty, i1 = ri + ty + 16, j0 = cj + tx, j1 = cj + tx + 16;
  if (i0 < NTOK && j0 < NTOK) F[i0 * NTOK + j0] = a00;
  if (i0 < NTOK && j1 < NTOK) F[i0 * NTOK + j1] = a01;
  if (i1 < NTOK && j0 < NTOK) F[i1 * NTOK + j0] = a10;
  if (i1 < NTOK && j1 < NTOK) F[i1 * NTOK + j1] = a11;
}

// ---------------- power iteration: sigma_max estimate -> 1/(1.1*sigma) ----------------
__global__ void k_pow(const float* __restrict__ Fbuf, float* __restrict__ nrmb) {
  int b = blockIdx.x;
  const float* F = Fbuf + (size_t)b * MAT;
  __shared__ float v[NTOK], u[NTOK];
  __shared__ float red[256];
  int tid = threadIdx.x;
  if (tid < NTOK) v[tid] = 1.f;
  __syncthreads();
  float lastsum = 1.f;
  for (int it = 0; it < 6; ++it) {
    float a = 0.f;
    if (tid < NTOK) { for (int j = 0; j < NTOK; ++j) a += F[tid * NTOK + j] * v[j]; }
    __syncthreads();
    if (tid < NTOK) u[tid] = a;
    __syncthreads();
    float a2 = 0.f;
    if (tid < NTOK) { for (int i = 0; i < NTOK; ++i) a2 += F[i * NTOK + tid] * u[i]; }
    red[tid] = (tid < NTOK) ? a2 * a2 : 0.f;
    __syncthreads();
    for (int s = 128; s > 0; s >>= 1) { if (tid < s) red[tid] += red[tid + s]; __syncthreads(); }
    float sum = red[0];
    lastsum = sum;
    float invn = rsqrtf(sum + 1e-30f);
    __syncthreads();
    if (tid < NTOK) v[tid] = a2 * invn;
    __syncthreads();
  }
  if (tid == 0) {
    float sig = sqrtf(sqrtf(lastsum));
    nrmb[b] = 1.f / (1.1f * sig + 1e-30f);
  }
}

// ---------------- X0 = F * invnorm (fallback path only) ----------------
__global__ void k_scale(const float* __restrict__ Fbuf, const float* __restrict__ nrmb,
                        float* __restrict__ X) {
  int b = blockIdx.y;
  int idx = blockIdx.x * 256 + threadIdx.x;
  if (idx < MAT) X[(size_t)b * MAT + idx] = Fbuf[(size_t)b * MAT + idx] * nrmb[b];
}

// ---------------- fused bf16-MFMA polar Newton-Schulz loop ----------------
// One block per batch. X and X^T live in LDS as bf16 [196][208]; H = X X^T goes to
// per-block global scratch (bf16, L2-resident). All three products per iteration are
// NT gemms (k-contiguous both operands): H=NT(X,X); X=1.5X-0.5*NT(H,Xt); Xt=1.5Xt-0.5*NT(Xt,H).
// Row-tile-per-wave ownership + register-cached A strips (needed for in-place safety in
// phase C: a wave only ever reads Xt rows it owns, after caching them).
__global__ __launch_bounds__(512, 1) void k_polar_fused(
    const float* __restrict__ Fbuf, const float* __restrict__ nrmb,
    short* __restrict__ Hall, float* __restrict__ Xout) {
  extern __shared__ short sm[];
  short* Xs  = sm;                       // [196][PADC]
  short* Xts = sm + NTOK * PADC;         // [196][PADC]
  int b = blockIdx.x;
  short* Hg = Hall + (size_t)b * (PADC * PADC);   // [208][208] bf16
  const float* F = Fbuf + (size_t)b * MAT;
  float* XO = Xout + (size_t)b * MAT;
  int tid = threadIdx.x;
  int wave = tid >> 6, ln15 = tid & 15, quad = (tid >> 4) & 3;

  // zero LDS (keeps all pads zero forever)
  for (int i = tid; i < (2 * NTOK * PADC) / 2; i += 512) ((int*)sm)[i] = 0;
  __syncthreads();
  float invc = nrmb[b];
  for (int idx = tid; idx < MAT; idx += 512) {
    int i = idx / NTOK, j = idx - i * NTOK;
    short h = f2bf(F[idx] * invc);
    Xs[i * PADC + j] = h;
    Xts[j * PADC + i] = h;
  }
  __syncthreads();

  for (int it = 0; it < POLAR_ITERS; ++it) {
    // ---- phase A: H = NT(X, X) ----
    for (int rt = wave; rt < NTILE; rt += 8) {
      int arow = rt * 16 + ln15;
      bool av = arow < NTOK;
      short8 areg[7];
      #pragma unroll
      for (int ks = 0; ks < 7; ++ks) {
        int kk = ks * 32 + quad * 8;
        areg[ks] = (av && kk < PADC) ? *(const short8*)(Xs + arow * PADC + kk) : s8zero();
      }
      for (int ct = 0; ct < NTILE; ++ct) {
        int brow = ct * 16 + ln15;
        bool bv = brow < NTOK;
        f32x4 acc = {0.f, 0.f, 0.f, 0.f};
        #pragma unroll
        for (int ks = 0; ks < 7; ++ks) {
          int kk = ks * 32 + quad * 8;
          short8 bfr = (bv && kk < PADC) ? *(const short8*)(Xs + brow * PADC + kk) : s8zero();
          acc = __builtin_amdgcn_mfma_f32_16x16x32_bf16(areg[ks], bfr, acc, 0, 0, 0);
        }
        #pragma unroll
        for (int r = 0; r < 4; ++r) {
          int row = rt * 16 + quad * 4 + r;
          Hg[row * PADC + ct * 16 + ln15] = f2bf(acc[r]);
        }
      }
    }
    __syncthreads();
    // ---- phase B: X = 1.5X - 0.5 * NT(H, Xt)   (in place by row-tile) ----
    for (int rt = wave; rt < NTILE; rt += 8) {
      int arow = rt * 16 + ln15;
      short8 areg[7];
      #pragma unroll
      for (int ks = 0; ks < 7; ++ks) {
        int kk = ks * 32 + quad * 8;
        areg[ks] = (kk < PADC) ? *(const short8*)(Hg + arow * PADC + kk) : s8zero();
      }
      for (int ct = 0; ct < NTILE; ++ct) {
        int brow = ct * 16 + ln15;
        bool bv = brow < NTOK;
        f32x4 acc = {0.f, 0.f, 0.f, 0.f};
        #pragma unroll
        for (int ks = 0; ks < 7; ++ks) {
          int kk = ks * 32 + quad * 8;
          short8 bfr = (bv && kk < PADC) ? *(const short8*)(Xts + brow * PADC + kk) : s8zero();
          acc = __builtin_amdgcn_mfma_f32_16x16x32_bf16(areg[ks], bfr, acc, 0, 0, 0);
        }
        #pragma unroll
        for (int r = 0; r < 4; ++r) {
          int row = rt * 16 + quad * 4 + r;
          if (row < NTOK) {
            int off = row * PADC + ct * 16 + ln15;
            float xo = bf2f(Xs[off]);
            Xs[off] = f2bf(1.5f * xo - 0.5f * acc[r]);
          }
        }
      }
    }
    __syncthreads();
    // ---- phase C: Xt = 1.5Xt - 0.5 * NT(Xt, H)  (in place by row-tile) ----
    for (int rt = wave; rt < NTILE; rt += 8) {
      int arow = rt * 16 + ln15;
      bool av = arow < NTOK;
      short8 areg[7];
      #pragma unroll
      for (int ks = 0; ks < 7; ++ks) {
        int kk = ks * 32 + quad * 8;
        areg[ks] = (av && kk < PADC) ? *(const short8*)(Xts + arow * PADC + kk) : s8zero();
      }
      for (int ct = 0; ct < NTILE; ++ct) {
        int brow = ct * 16 + ln15;             // H row, always allocated (<208)
        f32x4 acc = {0.f, 0.f, 0.f, 0.f};
        #pragma unroll
        for (int ks = 0; ks < 7; ++ks) {
          int kk = ks * 32 + quad * 8;
          short8 bfr = (kk < PADC) ? *(const short8*)(Hg + brow * PADC + kk) : s8zero();
          acc = __builtin_amdgcn_mfma_f32_16x16x32_bf16(areg[ks], bfr, acc, 0, 0, 0);
        }
        #pragma unroll
        for (int r = 0; r < 4; ++r) {
          int row = rt * 16 + quad * 4 + r;
          if (row < NTOK) {
            int off = row * PADC + ct * 16 + ln15;
            float xo = bf2f(Xts[off]);
            Xts[off] = f2bf(1.5f * xo - 0.5f * acc[r]);
          }
        }
      }
    }
    __syncthreads();
  }

  // write X back as fp32 for the polish iterations
  for (int idx = tid; idx < MAT; idx += 512) {
    int i = idx / NTOK, j = idx - i * NTOK;
    XO[idx] = bf2f(Xs[i * PADC + j]);
  }
}

// ---------------- Gp = X^T X (fp32, polish path) ----------------
__global__ void k_xtx(const float* __restrict__ Xb, float* __restrict__ Gp) {
  int b = blockIdx.y;
  const float* X = Xb + (size_t)b * MAT;
  int x = blockIdx.x, ti = 0;
  while (x >= ti + 1) { x -= ti + 1; ++ti; }
  int tj = x;
  int ri = ti * 32, cj = tj * 32;
  __shared__ float As[32][33], Bs[32][33];
  int tid = threadIdx.x, ty = tid >> 4, tx = tid & 15;
  float a00 = 0, a01 = 0, a10 = 0, a11 = 0;
  for (int k0 = 0; k0 < NTOK; k0 += 32) {
    for (int l = tid; l < 1024; l += 256) {
      int kk = l >> 5, ii = l & 31;
      int krow = k0 + kk;
      As[kk][ii] = (krow < NTOK && ri + ii < NTOK) ? X[(size_t)krow * NTOK + ri + ii] : 0.f;
      Bs[kk][ii] = (krow < NTOK && cj + ii < NTOK) ? X[(size_t)krow * NTOK + cj + ii] : 0.f;
    }
    __syncthreads();
    #pragma unroll
    for (int kk = 0; kk < 32; ++kk) {
      float p0 = As[kk][ty], p1 = As[kk][ty + 16];
      float q0 = Bs[kk][tx], q1 = Bs[kk][tx + 16];
      a00 += p0 * q0; a01 += p0 * q1; a10 += p1 * q0; a11 += p1 * q1;
    }
    __syncthreads();
  }
  float* G = Gp + (size_t)b * MAT;
  int i0 = ri + ty, i1 = ri + ty + 16, j0 = cj + tx, j1 = cj + tx + 16;
  if (i0 < NTOK && j0 < NTOK) { G[i0 * NTOK + j0] = a00; G[j0 * NTOK + i0] = a00; }
  if (i0 < NTOK && j1 < NTOK) { G[i0 * NTOK + j1] = a01; G[j1 * NTOK + i0] = a01; }
  if (i1 < NTOK && j0 < NTOK) { G[i1 * NTOK + j0] = a10; G[j0 * NTOK + i1] = a10; }
  if (i1 < NTOK && j1 < NTOK) { G[i1 * NTOK + j1] = a11; G[j1 * NTOK + i1] = a11; }
}

// ---------------- Xn = 1.5 X - 0.5 X * G (fp32, polish path) ----------------
__global__ void k_nsup(const float* __restrict__ Xb, const float* __restrict__ Gp,
                       float* __restrict__ Xn) {
  int b = blockIdx.y;
  const float* X = Xb + (size_t)b * MAT;
  const float* G = Gp + (size_t)b * MAT;
  int ti = blockIdx.x / 7, tj = blockIdx.x % 7;
  int ri = ti * 32, cj = tj * 32;
  __shared__ float As[32][33], Bs[32][33];
  int tid = threadIdx.x, ty = tid >> 4, tx = tid & 15;
  float a00 = 0, a01 = 0, a10 = 0, a11 = 0;
  for (int k0 = 0; k0 < NTOK; k0 += 32) {
    for (int l = tid; l < 1024; l += 256) {
      int rr = l >> 5, cc = l & 31;
      As[rr][cc] = (ri + rr < NTOK && k0 + cc < NTOK) ? X[(size_t)(ri + rr) * NTOK + k0 + cc] : 0.f;
      Bs[rr][cc] = (k0 + rr < NTOK && cj + cc < NTOK) ? G[(size_t)(k0 + rr) * NTOK + cj + cc] : 0.f;
    }
    __syncthreads();
    #pragma unroll
    for (int kk = 0; kk < 32; ++kk) {
      float p0 = As[ty][kk], p1 = As[ty + 16][kk];
      float q0 = Bs[kk][tx], q1 = Bs[kk][tx + 16];
      a00 += p0 * q0; a01 += p0 * q1; a10 += p1 * q0; a11 += p1 * q1;
    }
    __syncthreads();
  }
  float* O = Xn + (size_t)b * MAT;
  int i0 = ri + ty, i1 = ri + ty + 16, j0 = cj + tx, j1 = cj + tx + 16;
  if (i0 < NTOK && j0 < NTOK) O[i0 * NTOK + j0] = 1.5f * X[i0 * NTOK + j0] - 0.5f * a00;
  if (i0 < NTOK && j1 < NTOK) O[i0 * NTOK + j1] = 1.5f * X[i0 * NTOK + j1] - 0.5f * a01;
  if (i1 < NTOK && j0 < NTOK) O[i1 * NTOK + j0] = 1.5f * X[i1 * NTOK + j0] - 0.5f * a10;
  if (i1 < NTOK && j1 < NTOK) O[i1 * NTOK + j1] = 1.5f * X[i1 * NTOK + j1] - 0.5f * a11;
}

// ---------------- nuclear_b = sum(U .* F) ----------------
__global__ void k_nuc(const float* __restrict__ U, const float* __restrict__ Fbuf,
                      float* __restrict__ nucb) {
  int b = blockIdx.x;
  int tid = threadIdx.x;
  const float* Ub = U + (size_t)b * MAT;
  const float* Fb = Fbuf + (size_t)b * MAT;
  float acc = 0.f;
  for (int idx = tid; idx < MAT; idx += 256) acc += Ub[idx] * Fb[idx];
  __shared__ float red[256];
  red[tid] = acc;
  __syncthreads();
  for (int s = 128; s > 0; s >>= 1) { if (tid < s) red[tid] += red[tid + s]; __syncthreads(); }
  if (tid == 0) nucb[b] = red[0];
}

// ---------------- loss = mean_b relu(trP + trQ - 2*nuc) ----------------
__global__ void k_final(const float* __restrict__ trPb, const float* __restrict__ nucb,
                        float* __restrict__ out) {
  int tid = threadIdx.x;  // 64 threads = 1 wave
  float v = fmaxf(trPb[2 * tid] + trPb[2 * tid + 1] - 2.f * nucb[tid], 0.f);
  #pragma unroll
  for (int off = 32; off; off >>= 1) v += __shfl_down(v, off);
  if (tid == 0) out[0] = v * (1.f / 64.f);
}

extern "C" void kernel_launch(void* const* d_in, const int* in_sizes, int n_in,
                              void* d_out, int out_size, void* d_ws, size_t ws_size,
                              hipStream_t stream) {
  (void)in_sizes; (void)n_in; (void)out_size; (void)ws_size;
  const float* s = (const float*)d_in[0];
  const float* t = (const float*)d_in[1];
  const float* attn = (const float*)d_in[2];
  float* out = (float*)d_out;

  float* W = (float*)d_ws;
  float* Gbuf = W;                              // 128 * MAT   (G -> P -> L, in place)
  float* Fbuf = Gbuf + (size_t)128 * MAT;       // 64 * MAT
  float* Xbuf = Fbuf + (size_t)64 * MAT;        // 64 * MAT
  float* Xnew = Xbuf + (size_t)64 * MAT;        // 64 * MAT
  float* Gpol = Xnew + (size_t)64 * MAT;        // 64 * MAT (also reused as bf16 H scratch)
  float* wbuf = Gpol + (size_t)64 * MAT;        // 64 * 196
  float* trPb = wbuf + (size_t)NB * NTOK;       // 128
  float* nucb = trPb + 128;                     // 64
  float* nrmb = nucb + 64;                      // 64

  k_w<<<NB, 256, 0, stream>>>(attn, wbuf);
  k_gram<<<dim3(28, 128), 256, 0, stream>>>(s, t, wbuf, Gbuf);
  k_center<<<128, 256, 0, stream>>>(Gbuf, trPb);

  hipError_t chol_ok = hipFuncSetAttribute(
      reinterpret_cast<const void*>(k_chol_lds),
      hipFuncAttributeMaxDynamicSharedMemorySize, CHOL_LDS_BYTES);
  if (chol_ok == hipSuccess) {
    k_chol_lds<<<128, 256, CHOL_LDS_BYTES, stream>>>(Gbuf);
  } else {
    k_chol_global<<<128, 256, 0, stream>>>(Gbuf);
  }

  k_F<<<dim3(49, 64), 256, 0, stream>>>(Gbuf, Fbuf);
  k_pow<<<64, 256, 0, stream>>>(Fbuf, nrmb);

  hipError_t fused_ok = hipFuncSetAttribute(
      reinterpret_cast<const void*>(k_polar_fused),
      hipFuncAttributeMaxDynamicSharedMemorySize, POLAR_LDS_BYTES);

  const float* finalX;
  if (fused_ok == hipSuccess) {
    // 15 bf16-MFMA iterations fused in one launch, then 2 fp32 polish iterations
    k_polar_fused<<<NB, 512, POLAR_LDS_BYTES, stream>>>(Fbuf, nrmb, (short*)Gpol, Xbuf);
    k_xtx<<<dim3(28, 64), 256, 0, stream>>>(Xbuf, Gpol);
    k_nsup<<<dim3(49, 64), 256, 0, stream>>>(Xbuf, Gpol, Xnew);
    k_xtx<<<dim3(28, 64), 256, 0, stream>>>(Xnew, Gpol);
    k_nsup<<<dim3(49, 64), 256, 0, stream>>>(Xnew, Gpol, Xbuf);
    finalX = Xbuf;
  } else {
    // fallback: original fp32 loop
    k_scale<<<dim3(151, 64), 256, 0, stream>>>(Fbuf, nrmb, Xbuf);
    float* Xc = Xbuf;
    float* Xn = Xnew;
    for (int it = 0; it < POLAR_ITERS; ++it) {
      k_xtx<<<dim3(28, 64), 256, 0, stream>>>(Xc, Gpol);
      k_nsup<<<dim3(49, 64), 256, 0, stream>>>(Xc, Gpol, Xn);
      float* tmp = Xc; Xc = Xn; Xn = tmp;
    }
    finalX = Xc;
  }

  k_nuc<<<64, 256, 0, stream>>>(finalX, Fbuf, nucb);
  k_final<<<1, 64, 0, stream>>>(trPb, nucb, out);
}

// Round 6
// 1584.602 us; speedup vs baseline: 2.2715x; 1.3958x over previous
//
#include <hip/hip_runtime.h>
#include <hip/hip_bf16.h>
#include <math.h>

#define NTOK 196
#define NDIM 768
#define NB 64
#define NH 12
#define NA 197               // N+1
#define MAT (NTOK * NTOK)    // 38416
#define ATTN_HW (NA * NA)    // 38809
#define POLAR_ITERS 15
#define LDP 197              // padded leading dim for LDS Cholesky
#define CHOL_LDS_BYTES (NTOK * LDP * 4)

// fused polar constants
#define PADC 208             // 13*16 padded cols/K for MFMA tiling
#define NTILE 13
// two ping-pong buffers [196][208] bf16 = 163072 B (fits 160 KiB LDS)
#define POLAR_LDS_BYTES (2 * NTOK * PADC * 2)

typedef __attribute__((ext_vector_type(8))) short short8;
typedef __attribute__((ext_vector_type(4))) float f32x4;

__device__ inline short8 s8zero() { short8 z = {0,0,0,0,0,0,0,0}; return z; }

__device__ inline short f2bf(float f) {            // RNE fp32 -> bf16
  union { float f; unsigned u; } v; v.f = f;
  unsigned u = v.u;
  u += 0x7fffu + ((u >> 16) & 1u);
  return (short)(u >> 16);
}
__device__ inline float bf2f(short s) {
  union { unsigned u; float f; } v;
  v.u = ((unsigned)(unsigned short)s) << 16;
  return v.f;
}

// ---------------- w: CLS->patch attention, head-mean, normalized ----------------
__global__ void k_w(const float* __restrict__ attn, float* __restrict__ wbuf) {
  int b = blockIdx.x;
  int tid = threadIdx.x;
  __shared__ float red[256];
  float w0 = 0.f;
  if (tid < NTOK) {
    size_t base = (size_t)b * NH * ATTN_HW + 1 + tid;
    #pragma unroll
    for (int h = 0; h < NH; ++h) w0 += attn[base + (size_t)h * ATTN_HW];
    w0 *= (1.f / NH);
  }
  red[tid] = (tid < NTOK) ? w0 : 0.f;
  __syncthreads();
  for (int s = 128; s > 0; s >>= 1) { if (tid < s) red[tid] += red[tid + s]; __syncthreads(); }
  float S = red[0];
  if (tid < NTOK) wbuf[b * NTOK + tid] = w0 / (S + 1e-8f);
}

// ---------------- Grams: G = (w .* X)(w .* X)^T, symmetric triangle tiling ----------------
__global__ void k_gram(const float* __restrict__ s, const float* __restrict__ t,
                       const float* __restrict__ wbuf, float* __restrict__ Gbuf) {
  int slot = blockIdx.y, b = slot >> 1, src = slot & 1;
  const float* X = (src ? t : s) + (size_t)b * NTOK * NDIM;
  const float* wb = wbuf + b * NTOK;
  int x = blockIdx.x, ti = 0;
  while (x >= ti + 1) { x -= ti + 1; ++ti; }
  int tj = x;                      // tj <= ti
  int ri = ti * 32, rj = tj * 32;
  __shared__ float As[32][33], Bs[32][33];
  __shared__ float wA[32], wB[32];
  int tid = threadIdx.x;
  if (tid < 32) wA[tid] = (ri + tid < NTOK) ? wb[ri + tid] : 0.f;
  else if (tid < 64) { int i = tid - 32; wB[i] = (rj + i < NTOK) ? wb[rj + i] : 0.f; }
  __syncthreads();
  float a00 = 0, a01 = 0, a10 = 0, a11 = 0;
  int ty = tid >> 4, tx = tid & 15;
  for (int k0 = 0; k0 < NDIM; k0 += 32) {
    for (int l = tid; l < 1024; l += 256) {
      int ii = l >> 5, kk = l & 31;
      int r = ri + ii;
      As[ii][kk] = (r < NTOK) ? wA[ii] * X[(size_t)r * NDIM + k0 + kk] : 0.f;
      r = rj + ii;
      Bs[ii][kk] = (r < NTOK) ? wB[ii] * X[(size_t)r * NDIM + k0 + kk] : 0.f;
    }
    __syncthreads();
    #pragma unroll
    for (int kk = 0; kk < 32; ++kk) {
      float p0 = As[ty][kk], p1 = As[ty + 16][kk];
      float q0 = Bs[tx][kk], q1 = Bs[tx + 16][kk];
      a00 += p0 * q0; a01 += p0 * q1; a10 += p1 * q0; a11 += p1 * q1;
    }
    __syncthreads();
  }
  float* G = Gbuf + (size_t)slot * MAT;
  int i0 = ri + ty, i1 = ri + ty + 16, j0 = rj + tx, j1 = rj + tx + 16;
  if (i0 < NTOK && j0 < NTOK) { G[i0 * NTOK + j0] = a00; G[j0 * NTOK + i0] = a00; }
  if (i0 < NTOK && j1 < NTOK) { G[i0 * NTOK + j1] = a01; G[j1 * NTOK + i0] = a01; }
  if (i1 < NTOK && j0 < NTOK) { G[i1 * NTOK + j0] = a10; G[j0 * NTOK + i1] = a10; }
  if (i1 < NTOK && j1 < NTOK) { G[i1 * NTOK + j1] = a11; G[j1 * NTOK + i1] = a11; }
}

// ---------------- double-center in place: P = J G J (+ridge), record trace ----------------
__global__ void k_center(float* __restrict__ Gbuf, float* __restrict__ trPb) {
  int slot = blockIdx.x;
  float* A = Gbuf + (size_t)slot * MAT;
  __shared__ float r[NTOK];
  __shared__ float red[256];
  __shared__ float gsh, dsh;
  int tid = threadIdx.x;
  float acc = 0.f;
  if (tid < NTOK) {
    for (int m = 0; m < NTOK; ++m) acc += A[m * NTOK + tid];
    r[tid] = acc * (1.f / NTOK);
  }
  red[tid] = (tid < NTOK) ? acc * (1.f / NTOK) : 0.f;
  __syncthreads();
  for (int s = 128; s > 0; s >>= 1) { if (tid < s) red[tid] += red[tid + s]; __syncthreads(); }
  float g = red[0] * (1.f / NTOK);
  float tv = (tid < NTOK) ? (A[tid * NTOK + tid] - 2.f * r[tid] + g) : 0.f;
  __syncthreads();
  red[tid] = tv;
  __syncthreads();
  for (int s = 128; s > 0; s >>= 1) { if (tid < s) red[tid] += red[tid + s]; __syncthreads(); }
  if (tid == 0) {
    float tr = red[0];
    trPb[slot] = tr;
    gsh = g;
    dsh = 1e-4f * fmaxf(tr, 0.f) * (1.f / NTOK);
  }
  __syncthreads();
  float gg = gsh, dd = dsh;
  for (int idx = tid; idx < MAT; idx += 256) {
    int n = idx / NTOK, m = idx - n * NTOK;
    float v = A[idx] - r[n] - r[m] + gg;
    if (n == m) v += dd;
    A[idx] = v;
  }
}

// ---------------- full-LDS in-place Cholesky (lower), zero upper on writeback ----------------
__global__ void k_chol_lds(float* __restrict__ Gbuf) {
  extern __shared__ float Ash[];          // NTOK * LDP
  __shared__ float colv[NTOK];
  __shared__ float pivinv;
  int slot = blockIdx.x;
  float* A = Gbuf + (size_t)slot * MAT;
  int tid = threadIdx.x;
  for (int idx = tid; idx < MAT; idx += 256) {
    int i = idx / NTOK, j = idx - i * NTOK;
    Ash[i * LDP + j] = A[idx];
  }
  __syncthreads();
  int tx = tid & 15, ty = tid >> 4;
  for (int k = 0; k < NTOK; ++k) {
    if (tid == 0) {
      float d = fmaxf(Ash[k * LDP + k], 1e-20f);
      float sq = sqrtf(d);
      Ash[k * LDP + k] = sq;
      pivinv = 1.f / sq;
    }
    __syncthreads();
    float inv = pivinv;
    int i = k + 1 + tid;
    if (i < NTOK) {
      float v = Ash[i * LDP + k] * inv;
      Ash[i * LDP + k] = v;
      colv[i] = v;
    }
    __syncthreads();
    int base = k + 1, nrem = NTOK - base;
    for (int ii = ty; ii < nrem; ii += 16) {
      float ci = colv[base + ii];
      int row = (base + ii) * LDP + base;
      for (int jj = tx; jj <= ii; jj += 16)
        Ash[row + jj] -= ci * colv[base + jj];
    }
    __syncthreads();
  }
  for (int idx = tid; idx < MAT; idx += 256) {
    int i = idx / NTOK, j = idx - i * NTOK;
    A[idx] = (j <= i) ? Ash[i * LDP + j] : 0.f;
  }
}

// ---------------- fallback: original global-memory Cholesky ----------------
__global__ void k_chol_global(float* __restrict__ Gbuf) {
  int slot = blockIdx.x;
  float* A = Gbuf + (size_t)slot * MAT;
  __shared__ float col[NTOK];
  __shared__ float piv;
  int tid = threadIdx.x;
  for (int k = 0; k < NTOK; ++k) {
    if (tid == 0) { float p = sqrtf(fmaxf(A[k * NTOK + k], 1e-20f)); A[k * NTOK + k] = p; piv = p; }
    __syncthreads();
    float inv = 1.f / piv;
    for (int i = k + 1 + tid; i < NTOK; i += 256) {
      float v = A[i * NTOK + k] * inv;
      A[i * NTOK + k] = v;
      col[i] = v;
    }
    for (int j = k + 1 + tid; j < NTOK; j += 256) A[k * NTOK + j] = 0.f;
    __syncthreads();
    int nrem = NTOK - 1 - k;
    int total = nrem * (nrem + 1) / 2;
    for (int tt = tid; tt < total; tt += 256) {
      int a = (int)((sqrtf(8.f * tt + 1.f) - 1.f) * 0.5f);
      while ((a + 1) * (a + 2) / 2 <= tt) ++a;
      while (a * (a + 1) / 2 > tt) --a;
      int bb = tt - a * (a + 1) / 2;
      int i = k + 1 + a, j = k + 1 + bb;
      A[i * NTOK + j] -= col[i] * col[j];
    }
    __syncthreads();
  }
}

// ---------------- F = Lp^T * Lq ----------------
__global__ void k_F(const float* __restrict__ Gbuf, float* __restrict__ Fbuf) {
  int b = blockIdx.y;
  const float* Lp = Gbuf + (size_t)(2 * b) * MAT;
  const float* Lq = Gbuf + (size_t)(2 * b + 1) * MAT;
  int ti = blockIdx.x / 7, tj = blockIdx.x % 7;
  int ri = ti * 32, cj = tj * 32;
  __shared__ float As[32][33], Bs[32][33];
  int tid = threadIdx.x, ty = tid >> 4, tx = tid & 15;
  float a00 = 0, a01 = 0, a10 = 0, a11 = 0;
  for (int k0 = 0; k0 < NTOK; k0 += 32) {
    for (int l = tid; l < 1024; l += 256) {
      int kk = l >> 5, ii = l & 31;
      int krow = k0 + kk;
      As[kk][ii] = (krow < NTOK && ri + ii < NTOK) ? Lp[(size_t)krow * NTOK + ri + ii] : 0.f;
      Bs[kk][ii] = (krow < NTOK && cj + ii < NTOK) ? Lq[(size_t)krow * NTOK + cj + ii] : 0.f;
    }
    __syncthreads();
    #pragma unroll
    for (int kk = 0; kk < 32; ++kk) {
      float p0 = As[kk][ty], p1 = As[kk][ty + 16];
      float q0 = Bs[kk][tx], q1 = Bs[kk][tx + 16];
      a00 += p0 * q0; a01 += p0 * q1; a10 += p1 * q0; a11 += p1 * q1;
    }
    __syncthreads();
  }
  float* F = Fbuf + (size_t)b * MAT;
  int i0 = ri + ty, i1 = ri + ty + 16, j0 = cj + tx, j1 = cj + tx + 16;
  if (i0 < NTOK && j0 < NTOK) F[i0 * NTOK + j0] = a00;
  if (i0 < NTOK && j1 < NTOK) F[i0 * NTOK + j1] = a01;
  if (i1 < NTOK && j0 < NTOK) F[i1 * NTOK + j0] = a10;
  if (i1 < NTOK && j1 < NTOK) F[i1 * NTOK + j1] = a11;
}

// ---------------- power iteration: sigma_max estimate -> 1/(1.1*sigma) ----------------
__global__ void k_pow(const float* __restrict__ Fbuf, float* __restrict__ nrmb) {
  int b = blockIdx.x;
  const float* F = Fbuf + (size_t)b * MAT;
  __shared__ float v[NTOK], u[NTOK];
  __shared__ float red[256];
  int tid = threadIdx.x;
  if (tid < NTOK) v[tid] = 1.f;
  __syncthreads();
  float lastsum = 1.f;
  for (int it = 0; it < 6; ++it) {
    float a = 0.f;
    if (tid < NTOK) { for (int j = 0; j < NTOK; ++j) a += F[tid * NTOK + j] * v[j]; }
    __syncthreads();
    if (tid < NTOK) u[tid] = a;
    __syncthreads();
    float a2 = 0.f;
    if (tid < NTOK) { for (int i = 0; i < NTOK; ++i) a2 += F[i * NTOK + tid] * u[i]; }
    red[tid] = (tid < NTOK) ? a2 * a2 : 0.f;
    __syncthreads();
    for (int s = 128; s > 0; s >>= 1) { if (tid < s) red[tid] += red[tid + s]; __syncthreads(); }
    float sum = red[0];
    lastsum = sum;
    float invn = rsqrtf(sum + 1e-30f);
    __syncthreads();
    if (tid < NTOK) v[tid] = a2 * invn;
    __syncthreads();
  }
  if (tid == 0) {
    float sig = sqrtf(sqrtf(lastsum));
    nrmb[b] = 1.f / (1.1f * sig + 1e-30f);
  }
}

// ---------------- X0 = F * invnorm (fallback path only) ----------------
__global__ void k_scale(const float* __restrict__ Fbuf, const float* __restrict__ nrmb,
                        float* __restrict__ X) {
  int b = blockIdx.y;
  int idx = blockIdx.x * 256 + threadIdx.x;
  if (idx < MAT) X[(size_t)b * MAT + idx] = Fbuf[(size_t)b * MAT + idx] * nrmb[b];
}

// ---------------- fused bf16-MFMA polar Newton-Schulz loop (all-LDS, ping-pong) ----------------
// One block per batch. Two bf16 buffers [196][208]; cur = X, nxt = scratch.
//   phase A: nxt = H = NT(cur, cur) = X X^T           (vectorized NT)
//   phase B: nxt = 1.5*cur - 0.5 * H * cur  (NN: A = H rows vectorized+register-cached,
//            B = cur COLUMNS via strided u16 loads; output overwrites H, which is safe
//            because each wave register-caches exactly the H rows it later overwrites,
//            and cur is never written in phase B)
//   swap(cur, nxt)
// NOTE (round 4/5 bug): X*H = X*(X X^T) is NOT the NS product; the NS map needs
// H*X = (X X^T) X. Phase B computes H*X.
__global__ __launch_bounds__(512, 1) void k_polar_fused(
    const float* __restrict__ Fbuf, const float* __restrict__ nrmb,
    float* __restrict__ Xout) {
  extern __shared__ short sm[];
  short* bufA = sm;                      // [196][PADC]
  short* bufB = sm + NTOK * PADC;        // [196][PADC]
  int b = blockIdx.x;
  const float* F = Fbuf + (size_t)b * MAT;
  float* XO = Xout + (size_t)b * MAT;
  int tid = threadIdx.x;
  int wave = tid >> 6, ln15 = tid & 15, quad = (tid >> 4) & 3;
  int rt0 = wave, rt1 = wave + 8;
  bool has2 = (rt1 < NTILE);             // waves 0..4 own a second row-tile

  // zero both buffers (pads stay zero forever)
  for (int i = tid; i < (2 * NTOK * PADC) / 2; i += 512) ((int*)sm)[i] = 0;
  __syncthreads();
  float invc = nrmb[b];
  for (int idx = tid; idx < MAT; idx += 512) {
    int i = idx / NTOK, j = idx - i * NTOK;
    bufA[i * PADC + j] = f2bf(F[idx] * invc);
  }
  __syncthreads();

  short* cur = bufA;
  short* nxt = bufB;

  int arow0 = rt0 * 16 + ln15;           // <= 127 < NTOK always
  int arow1 = rt1 * 16 + ln15;           // up to 207
  bool av1 = has2 && (arow1 < NTOK);

  for (int it = 0; it < POLAR_ITERS; ++it) {
    // ---- phase A: nxt = H = X X^T (NT) ----
    {
      short8 a0[7], a1[7];
      #pragma unroll
      for (int ks = 0; ks < 7; ++ks) {
        int kk = ks * 32 + quad * 8;
        a0[ks] = (kk < PADC) ? *(const short8*)(cur + arow0 * PADC + kk) : s8zero();
        a1[ks] = (av1 && kk < PADC) ? *(const short8*)(cur + arow1 * PADC + kk) : s8zero();
      }
      for (int ct = 0; ct < NTILE; ++ct) {
        int brow = ct * 16 + ln15;
        bool bv = brow < NTOK;
        f32x4 acc0 = {0.f, 0.f, 0.f, 0.f};
        f32x4 acc1 = {0.f, 0.f, 0.f, 0.f};
        #pragma unroll
        for (int ks = 0; ks < 7; ++ks) {
          int kk = ks * 32 + quad * 8;
          short8 bfr = (bv && kk < PADC) ? *(const short8*)(cur + brow * PADC + kk) : s8zero();
          acc0 = __builtin_amdgcn_mfma_f32_16x16x32_bf16(a0[ks], bfr, acc0, 0, 0, 0);
          if (has2)
            acc1 = __builtin_amdgcn_mfma_f32_16x16x32_bf16(a1[ks], bfr, acc1, 0, 0, 0);
        }
        int col = ct * 16 + ln15;
        #pragma unroll
        for (int r = 0; r < 4; ++r) {
          int row = rt0 * 16 + quad * 4 + r;          // < NTOK for rt0 <= 7
          nxt[row * PADC + col] = f2bf(acc0[r]);
        }
        if (has2) {
          #pragma unroll
          for (int r = 0; r < 4; ++r) {
            int row = rt1 * 16 + quad * 4 + r;
            if (row < NTOK) nxt[row * PADC + col] = f2bf(acc1[r]);
          }
        }
      }
    }
    __syncthreads();
    // ---- phase B: nxt = 1.5*cur - 0.5 * H * cur (NN), overwriting H ----
    {
      short8 h0[7], h1[7];                 // register-cache own H rows (then free to overwrite)
      #pragma unroll
      for (int ks = 0; ks < 7; ++ks) {
        int kk = ks * 32 + quad * 8;
        h0[ks] = (kk < PADC) ? *(const short8*)(nxt + arow0 * PADC + kk) : s8zero();
        h1[ks] = (av1 && kk < PADC) ? *(const short8*)(nxt + arow1 * PADC + kk) : s8zero();
      }
      for (int ct = 0; ct < NTILE; ++ct) {
        int col = ct * 16 + ln15;
        // strided B fragments: B[n][k] = cur[k][ct*16+n], guard k < NTOK
        short8 bfr[7];
        #pragma unroll
        for (int ks = 0; ks < 7; ++ks) {
          int kk = ks * 32 + quad * 8;
          short8 v = s8zero();
          #pragma unroll
          for (int j = 0; j < 8; ++j) {
            int k = kk + j;
            if (k < NTOK) v[j] = cur[k * PADC + col];
          }
          bfr[ks] = v;
        }
        f32x4 acc0 = {0.f, 0.f, 0.f, 0.f};
        f32x4 acc1 = {0.f, 0.f, 0.f, 0.f};
        #pragma unroll
        for (int ks = 0; ks < 7; ++ks) {
          acc0 = __builtin_amdgcn_mfma_f32_16x16x32_bf16(h0[ks], bfr[ks], acc0, 0, 0, 0);
          if (has2)
            acc1 = __builtin_amdgcn_mfma_f32_16x16x32_bf16(h1[ks], bfr[ks], acc1, 0, 0, 0);
        }
        #pragma unroll
        for (int r = 0; r < 4; ++r) {
          int row = rt0 * 16 + quad * 4 + r;
          int off = row * PADC + col;
          nxt[off] = f2bf(1.5f * bf2f(cur[off]) - 0.5f * acc0[r]);
        }
        if (has2) {
          #pragma unroll
          for (int r = 0; r < 4; ++r) {
            int row = rt1 * 16 + quad * 4 + r;
            if (row < NTOK) {
              int off = row * PADC + col;
              nxt[off] = f2bf(1.5f * bf2f(cur[off]) - 0.5f * acc1[r]);
            }
          }
        }
      }
    }
    __syncthreads();
    short* tmp = cur; cur = nxt; nxt = tmp;
  }

  // write X back as fp32 for the polish iterations
  for (int idx = tid; idx < MAT; idx += 512) {
    int i = idx / NTOK, j = idx - i * NTOK;
    XO[idx] = bf2f(cur[i * PADC + j]);
  }
}

// ---------------- Gp = X^T X (fp32, polish path) ----------------
__global__ void k_xtx(const float* __restrict__ Xb, float* __restrict__ Gp) {
  int b = blockIdx.y;
  const float* X = Xb + (size_t)b * MAT;
  int x = blockIdx.x, ti = 0;
  while (x >= ti + 1) { x -= ti + 1; ++ti; }
  int tj = x;
  int ri = ti * 32, cj = tj * 32;
  __shared__ float As[32][33], Bs[32][33];
  int tid = threadIdx.x, ty = tid >> 4, tx = tid & 15;
  float a00 = 0, a01 = 0, a10 = 0, a11 = 0;
  for (int k0 = 0; k0 < NTOK; k0 += 32) {
    for (int l = tid; l < 1024; l += 256) {
      int kk = l >> 5, ii = l & 31;
      int krow = k0 + kk;
      As[kk][ii] = (krow < NTOK && ri + ii < NTOK) ? X[(size_t)krow * NTOK + ri + ii] : 0.f;
      Bs[kk][ii] = (krow < NTOK && cj + ii < NTOK) ? X[(size_t)krow * NTOK + cj + ii] : 0.f;
    }
    __syncthreads();
    #pragma unroll
    for (int kk = 0; kk < 32; ++kk) {
      float p0 = As[kk][ty], p1 = As[kk][ty + 16];
      float q0 = Bs[kk][tx], q1 = Bs[kk][tx + 16];
      a00 += p0 * q0; a01 += p0 * q1; a10 += p1 * q0; a11 += p1 * q1;
    }
    __syncthreads();
  }
  float* G = Gp + (size_t)b * MAT;
  int i0 = ri + ty, i1 = ri + ty + 16, j0 = cj + tx, j1 = cj + tx + 16;
  if (i0 < NTOK && j0 < NTOK) { G[i0 * NTOK + j0] = a00; G[j0 * NTOK + i0] = a00; }
  if (i0 < NTOK && j1 < NTOK) { G[i0 * NTOK + j1] = a01; G[j1 * NTOK + i0] = a01; }
  if (i1 < NTOK && j0 < NTOK) { G[i1 * NTOK + j0] = a10; G[j0 * NTOK + i1] = a10; }
  if (i1 < NTOK && j1 < NTOK) { G[i1 * NTOK + j1] = a11; G[j1 * NTOK + i1] = a11; }
}

// ---------------- Xn = 1.5 X - 0.5 X * G (fp32, polish path) ----------------
__global__ void k_nsup(const float* __restrict__ Xb, const float* __restrict__ Gp,
                       float* __restrict__ Xn) {
  int b = blockIdx.y;
  const float* X = Xb + (size_t)b * MAT;
  const float* G = Gp + (size_t)b * MAT;
  int ti = blockIdx.x / 7, tj = blockIdx.x % 7;
  int ri = ti * 32, cj = tj * 32;
  __shared__ float As[32][33], Bs[32][33];
  int tid = threadIdx.x, ty = tid >> 4, tx = tid & 15;
  float a00 = 0, a01 = 0, a10 = 0, a11 = 0;
  for (int k0 = 0; k0 < NTOK; k0 += 32) {
    for (int l = tid; l < 1024; l += 256) {
      int rr = l >> 5, cc = l & 31;
      As[rr][cc] = (ri + rr < NTOK && k0 + cc < NTOK) ? X[(size_t)(ri + rr) * NTOK + k0 + cc] : 0.f;
      Bs[rr][cc] = (k0 + rr < NTOK && cj + cc < NTOK) ? G[(size_t)(k0 + rr) * NTOK + cj + cc] : 0.f;
    }
    __syncthreads();
    #pragma unroll
    for (int kk = 0; kk < 32; ++kk) {
      float p0 = As[ty][kk], p1 = As[ty + 16][kk];
      float q0 = Bs[kk][tx], q1 = Bs[kk][tx + 16];
      a00 += p0 * q0; a01 += p0 * q1; a10 += p1 * q0; a11 += p1 * q1;
    }
    __syncthreads();
  }
  float* O = Xn + (size_t)b * MAT;
  int i0 = ri + ty, i1 = ri + ty + 16, j0 = cj + tx, j1 = cj + tx + 16;
  if (i0 < NTOK && j0 < NTOK) O[i0 * NTOK + j0] = 1.5f * X[i0 * NTOK + j0] - 0.5f * a00;
  if (i0 < NTOK && j1 < NTOK) O[i0 * NTOK + j1] = 1.5f * X[i0 * NTOK + j1] - 0.5f * a01;
  if (i1 < NTOK && j0 < NTOK) O[i1 * NTOK + j0] = 1.5f * X[i1 * NTOK + j0] - 0.5f * a10;
  if (i1 < NTOK && j1 < NTOK) O[i1 * NTOK + j1] = 1.5f * X[i1 * NTOK + j1] - 0.5f * a11;
}

// ---------------- nuclear_b = sum(U .* F) ----------------
__global__ void k_nuc(const float* __restrict__ U, const float* __restrict__ Fbuf,
                      float* __restrict__ nucb) {
  int b = blockIdx.x;
  int tid = threadIdx.x;
  const float* Ub = U + (size_t)b * MAT;
  const float* Fb = Fbuf + (size_t)b * MAT;
  float acc = 0.f;
  for (int idx = tid; idx < MAT; idx += 256) acc += Ub[idx] * Fb[idx];
  __shared__ float red[256];
  red[tid] = acc;
  __syncthreads();
  for (int s = 128; s > 0; s >>= 1) { if (tid < s) red[tid] += red[tid + s]; __syncthreads(); }
  if (tid == 0) nucb[b] = red[0];
}

// ---------------- loss = mean_b relu(trP + trQ - 2*nuc) ----------------
__global__ void k_final(const float* __restrict__ trPb, const float* __restrict__ nucb,
                        float* __restrict__ out) {
  int tid = threadIdx.x;  // 64 threads = 1 wave
  float v = fmaxf(trPb[2 * tid] + trPb[2 * tid + 1] - 2.f * nucb[tid], 0.f);
  #pragma unroll
  for (int off = 32; off; off >>= 1) v += __shfl_down(v, off);
  if (tid == 0) out[0] = v * (1.f / 64.f);
}

extern "C" void kernel_launch(void* const* d_in, const int* in_sizes, int n_in,
                              void* d_out, int out_size, void* d_ws, size_t ws_size,
                              hipStream_t stream) {
  (void)in_sizes; (void)n_in; (void)out_size; (void)ws_size;
  const float* s = (const float*)d_in[0];
  const float* t = (const float*)d_in[1];
  const float* attn = (const float*)d_in[2];
  float* out = (float*)d_out;

  float* W = (float*)d_ws;
  float* Gbuf = W;                              // 128 * MAT   (G -> P -> L, in place)
  float* Fbuf = Gbuf + (size_t)128 * MAT;       // 64 * MAT
  float* Xbuf = Fbuf + (size_t)64 * MAT;        // 64 * MAT
  float* Xnew = Xbuf + (size_t)64 * MAT;        // 64 * MAT
  float* Gpol = Xnew + (size_t)64 * MAT;        // 64 * MAT (polish scratch)
  float* wbuf = Gpol + (size_t)64 * MAT;        // 64 * 196
  float* trPb = wbuf + (size_t)NB * NTOK;       // 128
  float* nucb = trPb + 128;                     // 64
  float* nrmb = nucb + 64;                      // 64

  k_w<<<NB, 256, 0, stream>>>(attn, wbuf);
  k_gram<<<dim3(28, 128), 256, 0, stream>>>(s, t, wbuf, Gbuf);
  k_center<<<128, 256, 0, stream>>>(Gbuf, trPb);

  hipError_t chol_ok = hipFuncSetAttribute(
      reinterpret_cast<const void*>(k_chol_lds),
      hipFuncAttributeMaxDynamicSharedMemorySize, CHOL_LDS_BYTES);
  if (chol_ok == hipSuccess) {
    k_chol_lds<<<128, 256, CHOL_LDS_BYTES, stream>>>(Gbuf);
  } else {
    k_chol_global<<<128, 256, 0, stream>>>(Gbuf);
  }

  k_F<<<dim3(49, 64), 256, 0, stream>>>(Gbuf, Fbuf);
  k_pow<<<64, 256, 0, stream>>>(Fbuf, nrmb);

  hipError_t fused_ok = hipFuncSetAttribute(
      reinterpret_cast<const void*>(k_polar_fused),
      hipFuncAttributeMaxDynamicSharedMemorySize, POLAR_LDS_BYTES);

  const float* finalX;
  if (fused_ok == hipSuccess) {
    // 15 bf16-MFMA iterations fused in one launch, then 2 fp32 polish iterations
    k_polar_fused<<<NB, 512, POLAR_LDS_BYTES, stream>>>(Fbuf, nrmb, Xbuf);
    k_xtx<<<dim3(28, 64), 256, 0, stream>>>(Xbuf, Gpol);
    k_nsup<<<dim3(49, 64), 256, 0, stream>>>(Xbuf, Gpol, Xnew);
    k_xtx<<<dim3(28, 64), 256, 0, stream>>>(Xnew, Gpol);
    k_nsup<<<dim3(49, 64), 256, 0, stream>>>(Xnew, Gpol, Xbuf);
    finalX = Xbuf;
  } else {
    // fallback: original fp32 loop
    k_scale<<<dim3(151, 64), 256, 0, stream>>>(Fbuf, nrmb, Xbuf);
    float* Xc = Xbuf;
    float* Xn = Xnew;
    for (int it = 0; it < POLAR_ITERS; ++it) {
      k_xtx<<<dim3(28, 64), 256, 0, stream>>>(Xc, Gpol);
      k_nsup<<<dim3(49, 64), 256, 0, stream>>>(Xc, Gpol, Xn);
      float* tmp = Xc; Xc = Xn; Xn = tmp;
    }
    finalX = Xc;
  }

  k_nuc<<<64, 256, 0, stream>>>(finalX, Fbuf, nucb);
  k_final<<<1, 64, 0, stream>>>(trPb, nucb, out);
}